// Round 17
// baseline (154.113 us; speedup 1.0000x reference)
//
#include <hip/hip_runtime.h>
#include <hip/hip_bf16.h>

#define Bq 4
#define Sq 2048
#define Dq 512
#define Hq 8
#define HDq 64
#define Pq 64

typedef __attribute__((ext_vector_type(8))) short short8;
typedef __attribute__((ext_vector_type(4))) float f32x4;

__device__ inline unsigned short f2bf(float f) {
  unsigned int u = __float_as_uint(f);
  unsigned int r = u + 0x7FFFu + ((u >> 16) & 1u);
  return (unsigned short)(r >> 16);
}
__device__ inline float bf2f(unsigned short s) {
  return __uint_as_float(((unsigned int)s) << 16);
}
__device__ inline short8 ld8f(const float* __restrict__ p) {
  const float4 a = *(const float4*)p;
  const float4 b = *(const float4*)(p + 4);
  short8 r;
  r[0] = (short)f2bf(a.x); r[1] = (short)f2bf(a.y); r[2] = (short)f2bf(a.z); r[3] = (short)f2bf(a.w);
  r[4] = (short)f2bf(b.x); r[5] = (short)f2bf(b.y); r[6] = (short)f2bf(b.z); r[7] = (short)f2bf(b.w);
  return r;
}

// ------- fused prep (qpe/kpe->bf16, mask->bias) + weight convert/transpose -------
__global__ __launch_bounds__(256) void prep_conv(const float* __restrict__ qpe,
                                                 const float* __restrict__ kpe,
                                                 const int* __restrict__ mask,
                                                 const float* __restrict__ Wq,
                                                 const float* __restrict__ Wk,
                                                 const float* __restrict__ Wv,
                                                 const float* __restrict__ Wo,
                                                 unsigned short* __restrict__ qpeb,
                                                 unsigned short* __restrict__ kpeb,
                                                 float* __restrict__ mb,
                                                 unsigned short* __restrict__ Wqt,
                                                 unsigned short* __restrict__ Wkt,
                                                 unsigned short* __restrict__ Wvt,
                                                 unsigned short* __restrict__ Wot) {
  __shared__ float tile[32][33];
  const int bid = blockIdx.x;
  if (bid < 256) {
    int i = bid * 256 + threadIdx.x;
    *(short8*)&qpeb[(size_t)i * 8] = ld8f(qpe + (size_t)i * 8);
  } else if (bid < 512) {
    int i = (bid - 256) * 256 + threadIdx.x;
    *(short8*)&kpeb[(size_t)i * 8] = ld8f(kpe + (size_t)i * 8);
  } else if (bid < 544) {
    int i = (bid - 512) * 256 + threadIdx.x;
    mb[i] = ((float)mask[i] - 1.0f) * 1.442695041e8f;  // (mask-1)*1e8*log2e
  } else {
    const int cid = bid - 544;
    const int x = cid & 15, y = (cid >> 4) & 15, z = cid >> 8;
    const float* W = z == 0 ? Wq : z == 1 ? Wk : z == 2 ? Wv : Wo;
    unsigned short* Wt = z == 0 ? Wqt : z == 1 ? Wkt : z == 2 ? Wvt : Wot;
    const float scale = (z == 0) ? 0.125f : 1.0f;  // fold 1/sqrt(HD) into Wq
    const int tx = threadIdx.x & 31, ty = threadIdx.x >> 5;
    const int n0 = x * 32, k0 = y * 32;
    for (int j = 0; j < 4; ++j)
      tile[ty + j * 8][tx] = W[(size_t)(k0 + ty + j * 8) * Dq + n0 + tx];
    __syncthreads();
    for (int j = 0; j < 4; ++j)
      Wt[(size_t)(n0 + ty + j * 8) * Dq + k0 + tx] = f2bf(tile[tx][ty + j * 8] * scale);
  }
}

// ------- fused QKV projections: 128x128 tile, 4x4 acc/wave; z==2 writes V transposed -------
__global__ __launch_bounds__(256) void gemm_qkv(const float* __restrict__ Aq,
                                                const float* __restrict__ Ak,
                                                const float* __restrict__ Av,
                                                const unsigned short* __restrict__ Wqt,
                                                const unsigned short* __restrict__ Wkt,
                                                const unsigned short* __restrict__ Wvt,
                                                unsigned short* __restrict__ Qb,
                                                unsigned short* __restrict__ Kb,
                                                unsigned short* __restrict__ VbT) {
  __shared__ unsigned short Alds[128][72];
  __shared__ unsigned short Blds[128][72];
  const int z = blockIdx.z;
  const float* Ap = z == 0 ? Aq : z == 1 ? Ak : Av;
  const unsigned short* Wt = z == 0 ? Wqt : z == 1 ? Wkt : Wvt;
  unsigned short* Cb = z == 0 ? Qb : z == 1 ? Kb : VbT;
  const bool wt = (z == 2);
  const int tid = threadIdx.x;
  const int lane = tid & 63, wv = tid >> 6;
  const int wr = wv >> 1, wc = wv & 1;  // 2x2 waves, each 64x64
  const int l15 = lane & 15, lg = lane >> 4;
  const int row0 = blockIdx.x * 128, col0 = blockIdx.y * 128;
  f32x4 acc[4][4] = {};
  for (int k0 = 0; k0 < Dq; k0 += 64) {
    __syncthreads();
#pragma unroll
    for (int j = 0; j < 4; ++j) {
      int s = tid + j * 256;          // 1024 16B-segments per tile
      int r = s >> 3, c8 = (s & 7) * 8;
      const float* ap = Ap + (size_t)(row0 + r) * Dq + k0 + c8;
      float4 f0 = *(const float4*)ap;
      float4 f1 = *(const float4*)(ap + 4);
      short8 u;
      u[0] = (short)f2bf(f0.x); u[1] = (short)f2bf(f0.y);
      u[2] = (short)f2bf(f0.z); u[3] = (short)f2bf(f0.w);
      u[4] = (short)f2bf(f1.x); u[5] = (short)f2bf(f1.y);
      u[6] = (short)f2bf(f1.z); u[7] = (short)f2bf(f1.w);
      *(short8*)&Alds[r][c8] = u;
      *(uint4*)&Blds[r][c8] = *(const uint4*)&Wt[(size_t)(col0 + r) * Dq + k0 + c8];
    }
    __syncthreads();
#pragma unroll
    for (int kc = 0; kc < 2; ++kc) {
      short8 a[4], b[4];
#pragma unroll
      for (int mi = 0; mi < 4; ++mi)
        a[mi] = *(const short8*)&Alds[wr * 64 + mi * 16 + l15][kc * 32 + lg * 8];
#pragma unroll
      for (int ni = 0; ni < 4; ++ni)
        b[ni] = *(const short8*)&Blds[wc * 64 + ni * 16 + l15][kc * 32 + lg * 8];
#pragma unroll
      for (int mi = 0; mi < 4; ++mi)
#pragma unroll
        for (int ni = 0; ni < 4; ++ni)
          acc[mi][ni] = __builtin_amdgcn_mfma_f32_16x16x32_bf16(a[mi], b[ni], acc[mi][ni], 0, 0, 0);
    }
  }
  const int orow = row0 + wr * 64 + lg * 4;
  const int ocol = col0 + wc * 64 + l15;
  if (wt) {
    const int bidx = orow >> 11;
#pragma unroll
    for (int mi = 0; mi < 4; ++mi)
#pragma unroll
      for (int ni = 0; ni < 4; ++ni) {
        int gc = ocol + ni * 16;
        int s = (orow + mi * 16) & (Sq - 1);
        ushort4 w = {f2bf(acc[mi][ni][0]), f2bf(acc[mi][ni][1]),
                     f2bf(acc[mi][ni][2]), f2bf(acc[mi][ni][3])};
        *(ushort4*)&Cb[((size_t)(bidx * Dq + gc)) * Sq + s] = w;
      }
  } else {
#pragma unroll
    for (int mi = 0; mi < 4; ++mi)
#pragma unroll
      for (int ni = 0; ni < 4; ++ni)
#pragma unroll
        for (int rr = 0; rr < 4; ++rr) {
          int gr = orow + mi * 16 + rr, gc = ocol + ni * 16;
          Cb[(size_t)gr * Dq + gc] = f2bf(acc[mi][ni][rr]);
        }
  }
}

// ------- output projection + residual (fp32 out), 128x128 tile -------
__global__ __launch_bounds__(256) void gemm_wo(const unsigned short* __restrict__ Ab,
                                               const unsigned short* __restrict__ Wt,
                                               const float* __restrict__ res,
                                               float* __restrict__ Cf) {
  __shared__ unsigned short Alds[128][72];
  __shared__ unsigned short Blds[128][72];
  const int tid = threadIdx.x;
  const int lane = tid & 63, wv = tid >> 6;
  const int wr = wv >> 1, wc = wv & 1;
  const int l15 = lane & 15, lg = lane >> 4;
  const int row0 = blockIdx.x * 128, col0 = blockIdx.y * 128;
  f32x4 acc[4][4] = {};
  for (int k0 = 0; k0 < Dq; k0 += 64) {
    __syncthreads();
#pragma unroll
    for (int j = 0; j < 4; ++j) {
      int s = tid + j * 256;
      int r = s >> 3, c8 = (s & 7) * 8;
      *(uint4*)&Alds[r][c8] = *(const uint4*)&Ab[(size_t)(row0 + r) * Dq + k0 + c8];
      *(uint4*)&Blds[r][c8] = *(const uint4*)&Wt[(size_t)(col0 + r) * Dq + k0 + c8];
    }
    __syncthreads();
#pragma unroll
    for (int kc = 0; kc < 2; ++kc) {
      short8 a[4], b[4];
#pragma unroll
      for (int mi = 0; mi < 4; ++mi)
        a[mi] = *(const short8*)&Alds[wr * 64 + mi * 16 + l15][kc * 32 + lg * 8];
#pragma unroll
      for (int ni = 0; ni < 4; ++ni)
        b[ni] = *(const short8*)&Blds[wc * 64 + ni * 16 + l15][kc * 32 + lg * 8];
#pragma unroll
      for (int mi = 0; mi < 4; ++mi)
#pragma unroll
        for (int ni = 0; ni < 4; ++ni)
          acc[mi][ni] = __builtin_amdgcn_mfma_f32_16x16x32_bf16(a[mi], b[ni], acc[mi][ni], 0, 0, 0);
    }
  }
  const int orow = row0 + wr * 64 + lg * 4;
  const int ocol = col0 + wc * 64 + l15;
#pragma unroll
  for (int mi = 0; mi < 4; ++mi)
#pragma unroll
    for (int ni = 0; ni < 4; ++ni)
#pragma unroll
      for (int rr = 0; rr < 4; ++rr) {
        int gr = orow + mi * 16 + rr, gc = ocol + ni * 16;
        Cf[(size_t)gr * Dq + gc] = acc[mi][ni][rr] + res[(size_t)gr * Dq + gc];
      }
}

// ---------------- positional similarity (round-6 verified) ----------------
// simiB[b][q/16][k][q%16] fragment-blocked unnormalized exp + invsum[b][q].
__global__ __launch_bounds__(256) void possim(const unsigned short* __restrict__ qpe,
                                              const unsigned short* __restrict__ kpe,
                                              unsigned short* __restrict__ simiB,
                                              float* __restrict__ invsum) {
  __shared__ float wsum[4][16];
  const int tid = threadIdx.x, lane = tid & 63, wv = tid >> 6;
  const int l15 = lane & 15, lg = lane >> 4;
  const int b = blockIdx.y, q0 = blockIdx.x * 16;
  const unsigned short* qrow = qpe + ((size_t)(b * Sq + q0 + l15)) * Pq + lg * 8;
  short8 aq0 = *(const short8*)qrow;
  short8 aq1 = *(const short8*)(qrow + 32);
  unsigned short* sB = simiB + ((size_t)(b * (Sq / 16) + blockIdx.x)) * Sq * 16;
  float lsum[4] = {0.f, 0.f, 0.f, 0.f};
  for (int t = wv; t < Sq / 64; t += 4) {
    int k0 = t * 64;
    f32x4 sc[4] = {};
#pragma unroll
    for (int ng = 0; ng < 4; ++ng) {
      const unsigned short* krow = kpe + ((size_t)(b * Sq + k0 + ng * 16 + l15)) * Pq + lg * 8;
      short8 bk0 = *(const short8*)krow;
      short8 bk1 = *(const short8*)(krow + 32);
      sc[ng] = __builtin_amdgcn_mfma_f32_16x16x32_bf16(aq0, bk0, sc[ng], 0, 0, 0);
      sc[ng] = __builtin_amdgcn_mfma_f32_16x16x32_bf16(aq1, bk1, sc[ng], 0, 0, 0);
    }
#pragma unroll
    for (int ng = 0; ng < 4; ++ng) {
      float e0 = __expf(sc[ng][0]);
      float e1 = __expf(sc[ng][1]);
      float e2 = __expf(sc[ng][2]);
      float e3 = __expf(sc[ng][3]);
      lsum[0] += e0; lsum[1] += e1; lsum[2] += e2; lsum[3] += e3;
      ushort4 st = {f2bf(e0), f2bf(e1), f2bf(e2), f2bf(e3)};
      *(ushort4*)&sB[(size_t)(k0 + ng * 16 + l15) * 16 + lg * 4] = st;
    }
  }
  for (int rr = 0; rr < 4; ++rr)
    for (int m = 1; m < 16; m <<= 1) lsum[rr] += __shfl_xor(lsum[rr], m, 64);
  if (l15 == 0)
    for (int rr = 0; rr < 4; ++rr) wsum[wv][lg * 4 + rr] = lsum[rr];
  __syncthreads();
  if (tid < 16) {
    float tot = wsum[0][tid] + wsum[1][tid] + wsum[2][tid] + wsum[3][tid];
    invsum[b * Sq + q0 + tid] = 1.0f / tot;
  }
}

// ---------------- attention: K-SPLIT (2 halves), 512 threads, 128-q tile ----------------
// z = b*2 + kh; each block sums k in [kh*1024, kh*1024+1024). Writes UNNORMALIZED
// partial O (bf16) + partial lsum; combine kernel merges. Grid 1024 blocks -> 4/CU.
__global__ __launch_bounds__(512) void attn(const unsigned short* __restrict__ Qb,
                                            const unsigned short* __restrict__ Kb,
                                            const unsigned short* __restrict__ VbT,
                                            const unsigned short* __restrict__ simiB,
                                            const float* __restrict__ invsum,
                                            const float* __restrict__ mbias,
                                            unsigned short* __restrict__ Opart,
                                            float* __restrict__ lpart) {
  __shared__ unsigned short Klds[64][72];
  __shared__ unsigned short Vlds[64][72];
  __shared__ unsigned short Plds[8][16][72];
  const int tid = threadIdx.x, lane = tid & 63, wv = tid >> 6;  // wv 0..7
  const int l15 = lane & 15, lg = lane >> 4;
  const int q0 = blockIdx.x * 128, h = blockIdx.y;
  const int b = blockIdx.z >> 1, kh = blockIdx.z & 1;
  const int kbase = kh * (Sq / 2);
  const int qw = q0 + wv * 16;
  const int sr = tid >> 3, sc8 = (tid & 7) * 8;
  const unsigned short* Kg = Kb + ((size_t)(b * Sq + sr)) * Dq + h * HDq + sc8;   // +k0*Dq
  const unsigned short* Vg = VbT + ((size_t)(b * Dq + h * HDq + sr)) * Sq + sc8;  // +k0

  const unsigned short* qp = Qb + ((size_t)(b * Sq + qw + l15)) * Dq + h * HDq + lg * 8;
  short8 aq0 = *(const short8*)qp;
  short8 aq1 = *(const short8*)(qp + 32);
  float inv2[4];
#pragma unroll
  for (int rr = 0; rr < 4; ++rr)
    inv2[rr] = invsum[b * Sq + qw + lg * 4 + rr] * 1.442695041f;  // *log2e for exp2
  const unsigned short* sB =
      simiB + ((size_t)(b * (Sq / 16) + blockIdx.x * 8 + wv)) * Sq * 16 + lg * 4;
  const float* Mb = mbias + b * Sq;

  // prologue: first tile of this k-half into LDS
  {
    *(uint4*)&Klds[sr][sc8] = *(const uint4*)(Kg + (size_t)kbase * Dq);
    *(uint4*)&Vlds[sr][sc8] = *(const uint4*)(Vg + kbase);
  }
  f32x4 oacc[4] = {};
  float lsum[4] = {0.f, 0.f, 0.f, 0.f};
  for (int t = 0; t < Sq / 128; ++t) {  // 16 tiles of 64 keys
    const int k0 = kbase + t * 64;
    __syncthreads();  // LDS tile t visible to all waves
    uint4 nk0, nv0;
    const bool more = (t < Sq / 128 - 1);
    if (more) {  // issue next-tile loads; held in regs across this tile's compute
      nk0 = *(const uint4*)(Kg + (size_t)(k0 + 64) * Dq);
      nv0 = *(const uint4*)(Vg + (k0 + 64));
    }
    ushort4 sv4[4];
    float mbf[4];
#pragma unroll
    for (int ng = 0; ng < 4; ++ng) {
      int kk = k0 + ng * 16 + l15;
      sv4[ng] = *(const ushort4*)&sB[(size_t)kk * 16];
      mbf[ng] = Mb[kk];
    }
    // QK^T (Q pre-scaled by 1/8 via Wq)
    f32x4 sc[4] = {};
    __builtin_amdgcn_s_setprio(1);
#pragma unroll
    for (int ng = 0; ng < 4; ++ng) {
      short8 bk0 = *(const short8*)&Klds[ng * 16 + l15][lg * 8];
      short8 bk1 = *(const short8*)&Klds[ng * 16 + l15][32 + lg * 8];
      sc[ng] = __builtin_amdgcn_mfma_f32_16x16x32_bf16(aq0, bk0, sc[ng], 0, 0, 0);
      sc[ng] = __builtin_amdgcn_mfma_f32_16x16x32_bf16(aq1, bk1, sc[ng], 0, 0, 0);
    }
    __builtin_amdgcn_s_setprio(0);
    // softmax numerator: p = exp2((sc*sv)*inv2 + mb) -- raw v_exp_f32
#pragma unroll
    for (int ng = 0; ng < 4; ++ng) {
#pragma unroll
      for (int rr = 0; rr < 4; ++rr) {
        float sv = bf2f(rr == 0 ? sv4[ng].x : rr == 1 ? sv4[ng].y : rr == 2 ? sv4[ng].z
                                                                            : sv4[ng].w);
        float p = __builtin_amdgcn_exp2f(fmaf(sc[ng][rr] * sv, inv2[rr], mbf[ng]));
        lsum[rr] += p;
        Plds[wv][lg * 4 + rr][ng * 16 + l15] = f2bf(p);
      }
    }
    short8 pa0 = *(const short8*)&Plds[wv][l15][lg * 8];
    short8 pa1 = *(const short8*)&Plds[wv][l15][32 + lg * 8];
    __builtin_amdgcn_s_setprio(1);
#pragma unroll
    for (int dg = 0; dg < 4; ++dg) {
      short8 bv0 = *(const short8*)&Vlds[dg * 16 + l15][lg * 8];
      short8 bv1 = *(const short8*)&Vlds[dg * 16 + l15][32 + lg * 8];
      oacc[dg] = __builtin_amdgcn_mfma_f32_16x16x32_bf16(pa0, bv0, oacc[dg], 0, 0, 0);
      oacc[dg] = __builtin_amdgcn_mfma_f32_16x16x32_bf16(pa1, bv1, oacc[dg], 0, 0, 0);
    }
    __builtin_amdgcn_s_setprio(0);
    __syncthreads();  // all waves done reading K/V tile t
    if (more) {
      *(uint4*)&Klds[sr][sc8] = nk0;
      *(uint4*)&Vlds[sr][sc8] = nv0;
    }
  }
#pragma unroll
  for (int rr = 0; rr < 4; ++rr)
    for (int m = 1; m < 16; m <<= 1) lsum[rr] += __shfl_xor(lsum[rr], m, 64);
  // partial lsum: one lane per lg-group writes its 4 q-rows
  if (l15 == 0) {
#pragma unroll
    for (int rr = 0; rr < 4; ++rr)
      lpart[((size_t)((kh * Bq + b) * Hq + h)) * Sq + qw + lg * 4 + rr] = lsum[rr];
  }
  // unnormalized partial O (bf16)
#pragma unroll
  for (int dg = 0; dg < 4; ++dg)
    for (int rr = 0; rr < 4; ++rr) {
      int qg = qw + lg * 4 + rr;
      Opart[((size_t)((kh * Bq + b) * Sq + qg)) * Dq + h * HDq + dg * 16 + l15] =
          f2bf(oacc[dg][rr]);
    }
}

// ---------------- combine k-split partials: Ob = (o0+o1)/(l0+l1) ----------------
__global__ __launch_bounds__(256) void combine(const unsigned short* __restrict__ Opart,
                                               const float* __restrict__ lpart,
                                               unsigned short* __restrict__ Ob) {
  const size_t e8 = ((size_t)blockIdx.x * 256 + threadIdx.x) * 8;
  const int b = (int)(e8 >> 20);        // Sq*Dq = 2^20
  const int rem = (int)(e8 & (Sq * Dq - 1));
  const int q = rem >> 9;               // Dq = 512
  const int d = rem & (Dq - 1);
  const int h = d >> 6;
  const float l0 = lpart[((size_t)(b * Hq + h)) * Sq + q];
  const float l1 = lpart[((size_t)((Bq + b) * Hq + h)) * Sq + q];
  const float rinv = 1.0f / (l0 + l1);
  const short8 a0 = *(const short8*)&Opart[e8];
  const short8 a1 = *(const short8*)&Opart[(size_t)Bq * Sq * Dq + e8];
  short8 o;
#pragma unroll
  for (int j = 0; j < 8; ++j)
    o[j] = (short)f2bf((bf2f((unsigned short)a0[j]) + bf2f((unsigned short)a1[j])) * rinv);
  *(short8*)&Ob[e8] = o;
}

// ---------------- LayerNorm in-place on d_out ----------------
__global__ __launch_bounds__(256) void lnorm(float* __restrict__ X,
                                             const float* __restrict__ gamma,
                                             const float* __restrict__ beta) {
  const int tid = threadIdx.x, lane = tid & 63, wv = tid >> 6;
  const int row = blockIdx.x * 4 + wv;
  float* xr = X + (size_t)row * Dq + lane * 8;
  float4 x0 = *(float4*)xr;
  float4 x1 = *(float4*)(xr + 4);
  float s = x0.x + x0.y + x0.z + x0.w + x1.x + x1.y + x1.z + x1.w;
  float s2 = x0.x * x0.x + x0.y * x0.y + x0.z * x0.z + x0.w * x0.w +
             x1.x * x1.x + x1.y * x1.y + x1.z * x1.z + x1.w * x1.w;
  for (int m = 1; m < 64; m <<= 1) {
    s += __shfl_xor(s, m, 64);
    s2 += __shfl_xor(s2, m, 64);
  }
  float mu = s * (1.0f / 512.0f);
  float var = s2 * (1.0f / 512.0f) - mu * mu;
  float rstd = rsqrtf(var + 1e-5f);
  const float* g = gamma + lane * 8;
  const float* be = beta + lane * 8;
  float4 y0, y1;
  y0.x = (x0.x - mu) * rstd * g[0] + be[0];
  y0.y = (x0.y - mu) * rstd * g[1] + be[1];
  y0.z = (x0.z - mu) * rstd * g[2] + be[2];
  y0.w = (x0.w - mu) * rstd * g[3] + be[3];
  y1.x = (x1.x - mu) * rstd * g[4] + be[4];
  y1.y = (x1.y - mu) * rstd * g[5] + be[5];
  y1.z = (x1.z - mu) * rstd * g[6] + be[6];
  y1.w = (x1.w - mu) * rstd * g[7] + be[7];
  *(float4*)xr = y0;
  *(float4*)(xr + 4) = y1;
}

extern "C" void kernel_launch(void* const* d_in, const int* in_sizes, int n_in,
                              void* d_out, int out_size, void* d_ws, size_t ws_size,
                              hipStream_t stream) {
  const float* query = (const float*)d_in[0];
  const float* key = (const float*)d_in[1];
  const float* value = (const float*)d_in[2];
  const float* qpe = (const float*)d_in[3];
  const float* kpe = (const float*)d_in[4];
  const int* mask = (const int*)d_in[5];
  const float* Wq = (const float*)d_in[6];
  const float* Wk = (const float*)d_in[7];
  const float* Wv = (const float*)d_in[8];
  const float* Wo = (const float*)d_in[9];
  const float* gamma = (const float*)d_in[10];
  const float* beta = (const float*)d_in[11];
  float* out = (float*)d_out;

  char* ws = (char*)d_ws;
  size_t off = 0;
  unsigned short* Qb = (unsigned short*)(ws + off); off += (size_t)Bq * Sq * Dq * 2;     // 8MB
  unsigned short* Kb = (unsigned short*)(ws + off); off += (size_t)Bq * Sq * Dq * 2;     // 8MB
  unsigned short* VbT = (unsigned short*)(ws + off); off += (size_t)Bq * Sq * Dq * 2;    // 8MB
  unsigned short* Wqt = (unsigned short*)(ws + off); off += (size_t)Dq * Dq * 2;
  unsigned short* Wkt = (unsigned short*)(ws + off); off += (size_t)Dq * Dq * 2;
  unsigned short* Wvt = (unsigned short*)(ws + off); off += (size_t)Dq * Dq * 2;
  unsigned short* Wot = (unsigned short*)(ws + off); off += (size_t)Dq * Dq * 2;
  unsigned short* simiB = (unsigned short*)(ws + off); off += (size_t)Bq * Sq * Sq * 2;  // 32MB
  float* invsum = (float*)(ws + off); off += (size_t)Bq * Sq * 4;
  float* mbias = (float*)(ws + off); off += (size_t)Bq * Sq * 4;
  unsigned short* Ob = (unsigned short*)(ws + off); off += (size_t)Bq * Sq * Dq * 2;     // 8MB
  unsigned short* qpeb = (unsigned short*)(ws + off); off += (size_t)Bq * Sq * Pq * 2;   // 1MB
  unsigned short* kpeb = (unsigned short*)(ws + off); off += (size_t)Bq * Sq * Pq * 2;   // 1MB
  unsigned short* Opart = (unsigned short*)(ws + off); off += (size_t)2 * Bq * Sq * Dq * 2;  // 16MB
  float* lpart = (float*)(ws + off); off += (size_t)2 * Bq * Hq * Sq * 4;                // 512KB

  dim3 blk(256);
  prep_conv<<<dim3(544 + 1024), blk, 0, stream>>>(qpe, kpe, mask, Wq, Wk, Wv, Wo, qpeb, kpeb,
                                                  mbias, Wqt, Wkt, Wvt, Wot);
  possim<<<dim3(Sq / 16, Bq), blk, 0, stream>>>(qpeb, kpeb, simiB, invsum);
  gemm_qkv<<<dim3(64, 4, 3), blk, 0, stream>>>(query, key, value, Wqt, Wkt, Wvt, Qb, Kb, VbT);
  attn<<<dim3(Sq / 128, Hq, Bq * 2), dim3(512), 0, stream>>>(Qb, Kb, VbT, simiB, invsum, mbias,
                                                             Opart, lpart);
  combine<<<dim3(Bq * Sq * Dq / 8 / 256), blk, 0, stream>>>(Opart, lpart, Ob);
  gemm_wo<<<dim3(64, 4), blk, 0, stream>>>(Ob, Wot, query, out);
  lnorm<<<dim3(Bq * Sq / 4), blk, 0, stream>>>(out, gamma, beta);
}

// Round 20
// 146.013 us; speedup vs baseline: 1.0555x; 1.0555x over previous
//
#include <hip/hip_runtime.h>
#include <hip/hip_bf16.h>

#define Bq 4
#define Sq 2048
#define Dq 512
#define Hq 8
#define HDq 64
#define Pq 64

typedef __attribute__((ext_vector_type(8))) short short8;
typedef __attribute__((ext_vector_type(4))) float f32x4;

__device__ inline unsigned short f2bf(float f) {
  unsigned int u = __float_as_uint(f);
  unsigned int r = u + 0x7FFFu + ((u >> 16) & 1u);
  return (unsigned short)(r >> 16);
}
__device__ inline float bf2f(unsigned short s) {
  return __uint_as_float(((unsigned int)s) << 16);
}
__device__ inline short8 ld8f(const float* __restrict__ p) {
  const float4 a = *(const float4*)p;
  const float4 b = *(const float4*)(p + 4);
  short8 r;
  r[0] = (short)f2bf(a.x); r[1] = (short)f2bf(a.y); r[2] = (short)f2bf(a.z); r[3] = (short)f2bf(a.w);
  r[4] = (short)f2bf(b.x); r[5] = (short)f2bf(b.y); r[6] = (short)f2bf(b.z); r[7] = (short)f2bf(b.w);
  return r;
}

// ------- fused prep (qpe/kpe->bf16, mask->bias) + weight convert/transpose -------
__global__ __launch_bounds__(256) void prep_conv(const float* __restrict__ qpe,
                                                 const float* __restrict__ kpe,
                                                 const int* __restrict__ mask,
                                                 const float* __restrict__ Wq,
                                                 const float* __restrict__ Wk,
                                                 const float* __restrict__ Wv,
                                                 const float* __restrict__ Wo,
                                                 unsigned short* __restrict__ qpeb,
                                                 unsigned short* __restrict__ kpeb,
                                                 float* __restrict__ mb,
                                                 unsigned short* __restrict__ Wqt,
                                                 unsigned short* __restrict__ Wkt,
                                                 unsigned short* __restrict__ Wvt,
                                                 unsigned short* __restrict__ Wot) {
  __shared__ float tile[32][33];
  const int bid = blockIdx.x;
  if (bid < 256) {
    int i = bid * 256 + threadIdx.x;
    *(short8*)&qpeb[(size_t)i * 8] = ld8f(qpe + (size_t)i * 8);
  } else if (bid < 512) {
    int i = (bid - 256) * 256 + threadIdx.x;
    *(short8*)&kpeb[(size_t)i * 8] = ld8f(kpe + (size_t)i * 8);
  } else if (bid < 544) {
    int i = (bid - 512) * 256 + threadIdx.x;
    mb[i] = ((float)mask[i] - 1.0f) * 1.442695041e8f;  // (mask-1)*1e8*log2e
  } else {
    const int cid = bid - 544;
    const int x = cid & 15, y = (cid >> 4) & 15, z = cid >> 8;
    const float* W = z == 0 ? Wq : z == 1 ? Wk : z == 2 ? Wv : Wo;
    unsigned short* Wt = z == 0 ? Wqt : z == 1 ? Wkt : z == 2 ? Wvt : Wot;
    const float scale = (z == 0) ? 0.125f : 1.0f;  // fold 1/sqrt(HD) into Wq
    const int tx = threadIdx.x & 31, ty = threadIdx.x >> 5;
    const int n0 = x * 32, k0 = y * 32;
    for (int j = 0; j < 4; ++j)
      tile[ty + j * 8][tx] = W[(size_t)(k0 + ty + j * 8) * Dq + n0 + tx];
    __syncthreads();
    for (int j = 0; j < 4; ++j)
      Wt[(size_t)(n0 + ty + j * 8) * Dq + k0 + tx] = f2bf(tile[tx][ty + j * 8] * scale);
  }
}

// ------- fused QKV projections: 128x128 tile, 4x4 acc/wave; z==2 writes V transposed -------
__global__ __launch_bounds__(256) void gemm_qkv(const float* __restrict__ Aq,
                                                const float* __restrict__ Ak,
                                                const float* __restrict__ Av,
                                                const unsigned short* __restrict__ Wqt,
                                                const unsigned short* __restrict__ Wkt,
                                                const unsigned short* __restrict__ Wvt,
                                                unsigned short* __restrict__ Qb,
                                                unsigned short* __restrict__ Kb,
                                                unsigned short* __restrict__ VbT) {
  __shared__ unsigned short Alds[128][72];
  __shared__ unsigned short Blds[128][72];
  const int z = blockIdx.z;
  const float* Ap = z == 0 ? Aq : z == 1 ? Ak : Av;
  const unsigned short* Wt = z == 0 ? Wqt : z == 1 ? Wkt : Wvt;
  unsigned short* Cb = z == 0 ? Qb : z == 1 ? Kb : VbT;
  const bool wt = (z == 2);
  const int tid = threadIdx.x;
  const int lane = tid & 63, wv = tid >> 6;
  const int wr = wv >> 1, wc = wv & 1;  // 2x2 waves, each 64x64
  const int l15 = lane & 15, lg = lane >> 4;
  const int row0 = blockIdx.x * 128, col0 = blockIdx.y * 128;
  f32x4 acc[4][4] = {};
  for (int k0 = 0; k0 < Dq; k0 += 64) {
    __syncthreads();
#pragma unroll
    for (int j = 0; j < 4; ++j) {
      int s = tid + j * 256;          // 1024 16B-segments per tile
      int r = s >> 3, c8 = (s & 7) * 8;
      const float* ap = Ap + (size_t)(row0 + r) * Dq + k0 + c8;
      float4 f0 = *(const float4*)ap;
      float4 f1 = *(const float4*)(ap + 4);
      short8 u;
      u[0] = (short)f2bf(f0.x); u[1] = (short)f2bf(f0.y);
      u[2] = (short)f2bf(f0.z); u[3] = (short)f2bf(f0.w);
      u[4] = (short)f2bf(f1.x); u[5] = (short)f2bf(f1.y);
      u[6] = (short)f2bf(f1.z); u[7] = (short)f2bf(f1.w);
      *(short8*)&Alds[r][c8] = u;
      *(uint4*)&Blds[r][c8] = *(const uint4*)&Wt[(size_t)(col0 + r) * Dq + k0 + c8];
    }
    __syncthreads();
#pragma unroll
    for (int kc = 0; kc < 2; ++kc) {
      short8 a[4], b[4];
#pragma unroll
      for (int mi = 0; mi < 4; ++mi)
        a[mi] = *(const short8*)&Alds[wr * 64 + mi * 16 + l15][kc * 32 + lg * 8];
#pragma unroll
      for (int ni = 0; ni < 4; ++ni)
        b[ni] = *(const short8*)&Blds[wc * 64 + ni * 16 + l15][kc * 32 + lg * 8];
#pragma unroll
      for (int mi = 0; mi < 4; ++mi)
#pragma unroll
        for (int ni = 0; ni < 4; ++ni)
          acc[mi][ni] = __builtin_amdgcn_mfma_f32_16x16x32_bf16(a[mi], b[ni], acc[mi][ni], 0, 0, 0);
    }
  }
  const int orow = row0 + wr * 64 + lg * 4;
  const int ocol = col0 + wc * 64 + l15;
  if (wt) {
    const int bidx = orow >> 11;
#pragma unroll
    for (int mi = 0; mi < 4; ++mi)
#pragma unroll
      for (int ni = 0; ni < 4; ++ni) {
        int gc = ocol + ni * 16;
        int s = (orow + mi * 16) & (Sq - 1);
        ushort4 w = {f2bf(acc[mi][ni][0]), f2bf(acc[mi][ni][1]),
                     f2bf(acc[mi][ni][2]), f2bf(acc[mi][ni][3])};
        *(ushort4*)&Cb[((size_t)(bidx * Dq + gc)) * Sq + s] = w;
      }
  } else {
#pragma unroll
    for (int mi = 0; mi < 4; ++mi)
#pragma unroll
      for (int ni = 0; ni < 4; ++ni)
#pragma unroll
        for (int rr = 0; rr < 4; ++rr) {
          int gr = orow + mi * 16 + rr, gc = ocol + ni * 16;
          Cb[(size_t)gr * Dq + gc] = f2bf(acc[mi][ni][rr]);
        }
  }
}

// ------- output projection + residual (fp32 out), 128x128 tile -------
__global__ __launch_bounds__(256) void gemm_wo(const unsigned short* __restrict__ Ab,
                                               const unsigned short* __restrict__ Wt,
                                               const float* __restrict__ res,
                                               float* __restrict__ Cf) {
  __shared__ unsigned short Alds[128][72];
  __shared__ unsigned short Blds[128][72];
  const int tid = threadIdx.x;
  const int lane = tid & 63, wv = tid >> 6;
  const int wr = wv >> 1, wc = wv & 1;
  const int l15 = lane & 15, lg = lane >> 4;
  const int row0 = blockIdx.x * 128, col0 = blockIdx.y * 128;
  f32x4 acc[4][4] = {};
  for (int k0 = 0; k0 < Dq; k0 += 64) {
    __syncthreads();
#pragma unroll
    for (int j = 0; j < 4; ++j) {
      int s = tid + j * 256;
      int r = s >> 3, c8 = (s & 7) * 8;
      *(uint4*)&Alds[r][c8] = *(const uint4*)&Ab[(size_t)(row0 + r) * Dq + k0 + c8];
      *(uint4*)&Blds[r][c8] = *(const uint4*)&Wt[(size_t)(col0 + r) * Dq + k0 + c8];
    }
    __syncthreads();
#pragma unroll
    for (int kc = 0; kc < 2; ++kc) {
      short8 a[4], b[4];
#pragma unroll
      for (int mi = 0; mi < 4; ++mi)
        a[mi] = *(const short8*)&Alds[wr * 64 + mi * 16 + l15][kc * 32 + lg * 8];
#pragma unroll
      for (int ni = 0; ni < 4; ++ni)
        b[ni] = *(const short8*)&Blds[wc * 64 + ni * 16 + l15][kc * 32 + lg * 8];
#pragma unroll
      for (int mi = 0; mi < 4; ++mi)
#pragma unroll
        for (int ni = 0; ni < 4; ++ni)
          acc[mi][ni] = __builtin_amdgcn_mfma_f32_16x16x32_bf16(a[mi], b[ni], acc[mi][ni], 0, 0, 0);
    }
  }
  const int orow = row0 + wr * 64 + lg * 4;
  const int ocol = col0 + wc * 64 + l15;
#pragma unroll
  for (int mi = 0; mi < 4; ++mi)
#pragma unroll
    for (int ni = 0; ni < 4; ++ni)
#pragma unroll
      for (int rr = 0; rr < 4; ++rr) {
        int gr = orow + mi * 16 + rr, gc = ocol + ni * 16;
        Cf[(size_t)gr * Dq + gc] = acc[mi][ni][rr] + res[(size_t)gr * Dq + gc];
      }
}

// ---------------- positional similarity (round-6 verified) ----------------
// simiB[b][q/16][k][q%16] fragment-blocked unnormalized exp + invsum[b][q].
__global__ __launch_bounds__(256) void possim(const unsigned short* __restrict__ qpe,
                                              const unsigned short* __restrict__ kpe,
                                              unsigned short* __restrict__ simiB,
                                              float* __restrict__ invsum) {
  __shared__ float wsum[4][16];
  const int tid = threadIdx.x, lane = tid & 63, wv = tid >> 6;
  const int l15 = lane & 15, lg = lane >> 4;
  const int b = blockIdx.y, q0 = blockIdx.x * 16;
  const unsigned short* qrow = qpe + ((size_t)(b * Sq + q0 + l15)) * Pq + lg * 8;
  short8 aq0 = *(const short8*)qrow;
  short8 aq1 = *(const short8*)(qrow + 32);
  unsigned short* sB = simiB + ((size_t)(b * (Sq / 16) + blockIdx.x)) * Sq * 16;
  float lsum[4] = {0.f, 0.f, 0.f, 0.f};
  for (int t = wv; t < Sq / 64; t += 4) {
    int k0 = t * 64;
    f32x4 sc[4] = {};
#pragma unroll
    for (int ng = 0; ng < 4; ++ng) {
      const unsigned short* krow = kpe + ((size_t)(b * Sq + k0 + ng * 16 + l15)) * Pq + lg * 8;
      short8 bk0 = *(const short8*)krow;
      short8 bk1 = *(const short8*)(krow + 32);
      sc[ng] = __builtin_amdgcn_mfma_f32_16x16x32_bf16(aq0, bk0, sc[ng], 0, 0, 0);
      sc[ng] = __builtin_amdgcn_mfma_f32_16x16x32_bf16(aq1, bk1, sc[ng], 0, 0, 0);
    }
#pragma unroll
    for (int ng = 0; ng < 4; ++ng) {
      float e0 = __expf(sc[ng][0]);
      float e1 = __expf(sc[ng][1]);
      float e2 = __expf(sc[ng][2]);
      float e3 = __expf(sc[ng][3]);
      lsum[0] += e0; lsum[1] += e1; lsum[2] += e2; lsum[3] += e3;
      ushort4 st = {f2bf(e0), f2bf(e1), f2bf(e2), f2bf(e3)};
      *(ushort4*)&sB[(size_t)(k0 + ng * 16 + l15) * 16 + lg * 4] = st;
    }
  }
  for (int rr = 0; rr < 4; ++rr)
    for (int m = 1; m < 16; m <<= 1) lsum[rr] += __shfl_xor(lsum[rr], m, 64);
  if (l15 == 0)
    for (int rr = 0; rr < 4; ++rr) wsum[wv][lg * 4 + rr] = lsum[rr];
  __syncthreads();
  if (tid < 16) {
    float tot = wsum[0][tid] + wsum[1][tid] + wsum[2][tid] + wsum[3][tid];
    invsum[b * Sq + q0 + tid] = 1.0f / tot;
  }
}

// ---------------- attention: round-16 base + XCD-locality block remap ----------------
// Flat 512-block grid; id = h*64 + qt*4 + b. The 8 head-blocks sharing one simi panel
// (same qt,b) have ids congruent mod 8 -> same XCD under round-robin dispatch -> the
// 512KB simi panel is HBM-fetched once and L2-served for the other 7 heads.
__global__ __launch_bounds__(512) void attn(const unsigned short* __restrict__ Qb,
                                            const unsigned short* __restrict__ Kb,
                                            const unsigned short* __restrict__ VbT,
                                            const unsigned short* __restrict__ simiB,
                                            const float* __restrict__ invsum,
                                            const float* __restrict__ mbias,
                                            unsigned short* __restrict__ O) {
  __shared__ unsigned short Klds[64][72];
  __shared__ unsigned short Vlds[64][72];
  __shared__ unsigned short Plds[8][16][72];
  const int tid = threadIdx.x, lane = tid & 63, wv = tid >> 6;  // wv 0..7
  const int l15 = lane & 15, lg = lane >> 4;
  const int id = blockIdx.x;
  const int h = id >> 6;          // 8 heads
  const int rem = id & 63;
  const int qt = rem >> 2;        // 16 q-tiles
  const int b = rem & 3;          // 4 batches
  const int q0 = qt * 128;
  const int qw = q0 + wv * 16;
  const int sr = tid >> 3, sc8 = (tid & 7) * 8;
  const unsigned short* Kg = Kb + ((size_t)(b * Sq + sr)) * Dq + h * HDq + sc8;   // +k0*Dq
  const unsigned short* Vg = VbT + ((size_t)(b * Dq + h * HDq + sr)) * Sq + sc8;  // +k0

  const unsigned short* qp = Qb + ((size_t)(b * Sq + qw + l15)) * Dq + h * HDq + lg * 8;
  short8 aq0 = *(const short8*)qp;
  short8 aq1 = *(const short8*)(qp + 32);
  float inv2[4];
#pragma unroll
  for (int rr = 0; rr < 4; ++rr)
    inv2[rr] = invsum[b * Sq + qw + lg * 4 + rr] * 1.442695041f;  // *log2e for exp2
  const unsigned short* sB =
      simiB + ((size_t)(b * (Sq / 16) + qt * 8 + wv)) * Sq * 16 + lg * 4;
  const float* Mb = mbias + b * Sq;

  // prologue: tile 0 into LDS
  {
    *(uint4*)&Klds[sr][sc8] = *(const uint4*)Kg;
    *(uint4*)&Vlds[sr][sc8] = *(const uint4*)Vg;
  }
  f32x4 oacc[4] = {};
  float lsum[4] = {0.f, 0.f, 0.f, 0.f};
  for (int t = 0; t < Sq / 64; ++t) {
    const int k0 = t * 64;
    __syncthreads();  // LDS tile t visible to all waves
    uint4 nk0, nv0;
    const bool more = (t < Sq / 64 - 1);
    if (more) {  // issue next-tile loads; held in regs across this tile's compute
      nk0 = *(const uint4*)(Kg + (size_t)(k0 + 64) * Dq);
      nv0 = *(const uint4*)(Vg + (k0 + 64));
    }
    ushort4 sv4[4];
    float mbf[4];
#pragma unroll
    for (int ng = 0; ng < 4; ++ng) {
      int kk = k0 + ng * 16 + l15;
      sv4[ng] = *(const ushort4*)&sB[(size_t)kk * 16];
      mbf[ng] = Mb[kk];
    }
    // QK^T (Q pre-scaled by 1/8 via Wq)
    f32x4 sc[4] = {};
    __builtin_amdgcn_s_setprio(1);
#pragma unroll
    for (int ng = 0; ng < 4; ++ng) {
      short8 bk0 = *(const short8*)&Klds[ng * 16 + l15][lg * 8];
      short8 bk1 = *(const short8*)&Klds[ng * 16 + l15][32 + lg * 8];
      sc[ng] = __builtin_amdgcn_mfma_f32_16x16x32_bf16(aq0, bk0, sc[ng], 0, 0, 0);
      sc[ng] = __builtin_amdgcn_mfma_f32_16x16x32_bf16(aq1, bk1, sc[ng], 0, 0, 0);
    }
    __builtin_amdgcn_s_setprio(0);
    // softmax numerator: p = exp2((sc*sv)*inv2 + mb) -- raw v_exp_f32
#pragma unroll
    for (int ng = 0; ng < 4; ++ng) {
#pragma unroll
      for (int rr = 0; rr < 4; ++rr) {
        float sv = bf2f(rr == 0 ? sv4[ng].x : rr == 1 ? sv4[ng].y : rr == 2 ? sv4[ng].z
                                                                            : sv4[ng].w);
        float p = __builtin_amdgcn_exp2f(fmaf(sc[ng][rr] * sv, inv2[rr], mbf[ng]));
        lsum[rr] += p;
        Plds[wv][lg * 4 + rr][ng * 16 + l15] = f2bf(p);
      }
    }
    short8 pa0 = *(const short8*)&Plds[wv][l15][lg * 8];
    short8 pa1 = *(const short8*)&Plds[wv][l15][32 + lg * 8];
    __builtin_amdgcn_s_setprio(1);
#pragma unroll
    for (int dg = 0; dg < 4; ++dg) {
      short8 bv0 = *(const short8*)&Vlds[dg * 16 + l15][lg * 8];
      short8 bv1 = *(const short8*)&Vlds[dg * 16 + l15][32 + lg * 8];
      oacc[dg] = __builtin_amdgcn_mfma_f32_16x16x32_bf16(pa0, bv0, oacc[dg], 0, 0, 0);
      oacc[dg] = __builtin_amdgcn_mfma_f32_16x16x32_bf16(pa1, bv1, oacc[dg], 0, 0, 0);
    }
    __builtin_amdgcn_s_setprio(0);
    __syncthreads();  // all waves done reading K/V tile t
    if (more) {
      *(uint4*)&Klds[sr][sc8] = nk0;
      *(uint4*)&Vlds[sr][sc8] = nv0;
    }
  }
#pragma unroll
  for (int rr = 0; rr < 4; ++rr)
    for (int m = 1; m < 16; m <<= 1) lsum[rr] += __shfl_xor(lsum[rr], m, 64);
#pragma unroll
  for (int dg = 0; dg < 4; ++dg)
    for (int rr = 0; rr < 4; ++rr) {
      int qg = qw + lg * 4 + rr;
      O[((size_t)(b * Sq + qg)) * Dq + h * HDq + dg * 16 + l15] = f2bf(oacc[dg][rr] / lsum[rr]);
    }
}

// ---------------- LayerNorm in-place on d_out ----------------
__global__ __launch_bounds__(256) void lnorm(float* __restrict__ X,
                                             const float* __restrict__ gamma,
                                             const float* __restrict__ beta) {
  const int tid = threadIdx.x, lane = tid & 63, wv = tid >> 6;
  const int row = blockIdx.x * 4 + wv;
  float* xr = X + (size_t)row * Dq + lane * 8;
  float4 x0 = *(float4*)xr;
  float4 x1 = *(float4*)(xr + 4);
  float s = x0.x + x0.y + x0.z + x0.w + x1.x + x1.y + x1.z + x1.w;
  float s2 = x0.x * x0.x + x0.y * x0.y + x0.z * x0.z + x0.w * x0.w +
             x1.x * x1.x + x1.y * x1.y + x1.z * x1.z + x1.w * x1.w;
  for (int m = 1; m < 64; m <<= 1) {
    s += __shfl_xor(s, m, 64);
    s2 += __shfl_xor(s2, m, 64);
  }
  float mu = s * (1.0f / 512.0f);
  float var = s2 * (1.0f / 512.0f) - mu * mu;
  float rstd = rsqrtf(var + 1e-5f);
  const float* g = gamma + lane * 8;
  const float* be = beta + lane * 8;
  float4 y0, y1;
  y0.x = (x0.x - mu) * rstd * g[0] + be[0];
  y0.y = (x0.y - mu) * rstd * g[1] + be[1];
  y0.z = (x0.z - mu) * rstd * g[2] + be[2];
  y0.w = (x0.w - mu) * rstd * g[3] + be[3];
  y1.x = (x1.x - mu) * rstd * g[4] + be[4];
  y1.y = (x1.y - mu) * rstd * g[5] + be[5];
  y1.z = (x1.z - mu) * rstd * g[6] + be[6];
  y1.w = (x1.w - mu) * rstd * g[7] + be[7];
  *(float4*)xr = y0;
  *(float4*)(xr + 4) = y1;
}

extern "C" void kernel_launch(void* const* d_in, const int* in_sizes, int n_in,
                              void* d_out, int out_size, void* d_ws, size_t ws_size,
                              hipStream_t stream) {
  const float* query = (const float*)d_in[0];
  const float* key = (const float*)d_in[1];
  const float* value = (const float*)d_in[2];
  const float* qpe = (const float*)d_in[3];
  const float* kpe = (const float*)d_in[4];
  const int* mask = (const int*)d_in[5];
  const float* Wq = (const float*)d_in[6];
  const float* Wk = (const float*)d_in[7];
  const float* Wv = (const float*)d_in[8];
  const float* Wo = (const float*)d_in[9];
  const float* gamma = (const float*)d_in[10];
  const float* beta = (const float*)d_in[11];
  float* out = (float*)d_out;

  char* ws = (char*)d_ws;
  size_t off = 0;
  unsigned short* Qb = (unsigned short*)(ws + off); off += (size_t)Bq * Sq * Dq * 2;    // 8MB
  unsigned short* Kb = (unsigned short*)(ws + off); off += (size_t)Bq * Sq * Dq * 2;    // 8MB
  unsigned short* VbT = (unsigned short*)(ws + off); off += (size_t)Bq * Sq * Dq * 2;   // 8MB
  unsigned short* Wqt = (unsigned short*)(ws + off); off += (size_t)Dq * Dq * 2;
  unsigned short* Wkt = (unsigned short*)(ws + off); off += (size_t)Dq * Dq * 2;
  unsigned short* Wvt = (unsigned short*)(ws + off); off += (size_t)Dq * Dq * 2;
  unsigned short* Wot = (unsigned short*)(ws + off); off += (size_t)Dq * Dq * 2;
  unsigned short* simiB = (unsigned short*)(ws + off); off += (size_t)Bq * Sq * Sq * 2; // 32MB
  float* invsum = (float*)(ws + off); off += (size_t)Bq * Sq * 4;
  float* mbias = (float*)(ws + off); off += (size_t)Bq * Sq * 4;
  unsigned short* Ob = (unsigned short*)(ws + off); off += (size_t)Bq * Sq * Dq * 2;    // 8MB
  unsigned short* qpeb = (unsigned short*)(ws + off); off += (size_t)Bq * Sq * Pq * 2;  // 1MB
  unsigned short* kpeb = (unsigned short*)(ws + off); off += (size_t)Bq * Sq * Pq * 2;  // 1MB

  dim3 blk(256);
  prep_conv<<<dim3(544 + 1024), blk, 0, stream>>>(qpe, kpe, mask, Wq, Wk, Wv, Wo, qpeb, kpeb,
                                                  mbias, Wqt, Wkt, Wvt, Wot);
  possim<<<dim3(Sq / 16, Bq), blk, 0, stream>>>(qpeb, kpeb, simiB, invsum);
  gemm_qkv<<<dim3(64, 4, 3), blk, 0, stream>>>(query, key, value, Wqt, Wkt, Wvt, Qb, Kb, VbT);
  attn<<<dim3(512), dim3(512), 0, stream>>>(Qb, Kb, VbT, simiB, invsum, mbias, Ob);
  gemm_wo<<<dim3(64, 4), blk, 0, stream>>>(Ob, Wot, query, out);
  lnorm<<<dim3(Bq * Sq / 4), blk, 0, stream>>>(out, gamma, beta);
}

// Round 21
// 143.656 us; speedup vs baseline: 1.0728x; 1.0164x over previous
//
#include <hip/hip_runtime.h>
#include <hip/hip_bf16.h>

#define Bq 4
#define Sq 2048
#define Dq 512
#define Hq 8
#define HDq 64
#define Pq 64

typedef __attribute__((ext_vector_type(8))) short short8;
typedef __attribute__((ext_vector_type(4))) float f32x4;

__device__ inline unsigned short f2bf(float f) {
  unsigned int u = __float_as_uint(f);
  unsigned int r = u + 0x7FFFu + ((u >> 16) & 1u);
  return (unsigned short)(r >> 16);
}
// compiler-lowered bf16 conversion (backend emits native cvt with hazard handling)
__device__ inline unsigned short f2bfh(float f) {
  __hip_bfloat16 h = __float2bfloat16(f);
  return *reinterpret_cast<unsigned short*>(&h);
}
__device__ inline float bf2f(unsigned short s) {
  return __uint_as_float(((unsigned int)s) << 16);
}
__device__ inline short8 ld8f(const float* __restrict__ p) {
  const float4 a = *(const float4*)p;
  const float4 b = *(const float4*)(p + 4);
  short8 r;
  r[0] = (short)f2bf(a.x); r[1] = (short)f2bf(a.y); r[2] = (short)f2bf(a.z); r[3] = (short)f2bf(a.w);
  r[4] = (short)f2bf(b.x); r[5] = (short)f2bf(b.y); r[6] = (short)f2bf(b.z); r[7] = (short)f2bf(b.w);
  return r;
}

// ------- fused prep (qpe/kpe->bf16, mask->bias) + weight convert/transpose -------
__global__ __launch_bounds__(256) void prep_conv(const float* __restrict__ qpe,
                                                 const float* __restrict__ kpe,
                                                 const int* __restrict__ mask,
                                                 const float* __restrict__ Wq,
                                                 const float* __restrict__ Wk,
                                                 const float* __restrict__ Wv,
                                                 const float* __restrict__ Wo,
                                                 unsigned short* __restrict__ qpeb,
                                                 unsigned short* __restrict__ kpeb,
                                                 float* __restrict__ mb,
                                                 unsigned short* __restrict__ Wqt,
                                                 unsigned short* __restrict__ Wkt,
                                                 unsigned short* __restrict__ Wvt,
                                                 unsigned short* __restrict__ Wot) {
  __shared__ float tile[32][33];
  const int bid = blockIdx.x;
  if (bid < 256) {
    int i = bid * 256 + threadIdx.x;
    *(short8*)&qpeb[(size_t)i * 8] = ld8f(qpe + (size_t)i * 8);
  } else if (bid < 512) {
    int i = (bid - 256) * 256 + threadIdx.x;
    *(short8*)&kpeb[(size_t)i * 8] = ld8f(kpe + (size_t)i * 8);
  } else if (bid < 544) {
    int i = (bid - 512) * 256 + threadIdx.x;
    mb[i] = ((float)mask[i] - 1.0f) * 1.442695041e8f;  // (mask-1)*1e8*log2e
  } else {
    const int cid = bid - 544;
    const int x = cid & 15, y = (cid >> 4) & 15, z = cid >> 8;
    const float* W = z == 0 ? Wq : z == 1 ? Wk : z == 2 ? Wv : Wo;
    unsigned short* Wt = z == 0 ? Wqt : z == 1 ? Wkt : z == 2 ? Wvt : Wot;
    const float scale = (z == 0) ? 0.125f : 1.0f;  // fold 1/sqrt(HD) into Wq
    const int tx = threadIdx.x & 31, ty = threadIdx.x >> 5;
    const int n0 = x * 32, k0 = y * 32;
    for (int j = 0; j < 4; ++j)
      tile[ty + j * 8][tx] = W[(size_t)(k0 + ty + j * 8) * Dq + n0 + tx];
    __syncthreads();
    for (int j = 0; j < 4; ++j)
      Wt[(size_t)(n0 + ty + j * 8) * Dq + k0 + tx] = f2bf(tile[tx][ty + j * 8] * scale);
  }
}

// ------- fused QKV projections: 128x128 tile, 4x4 acc/wave; z==2 writes V transposed -------
__global__ __launch_bounds__(256) void gemm_qkv(const float* __restrict__ Aq,
                                                const float* __restrict__ Ak,
                                                const float* __restrict__ Av,
                                                const unsigned short* __restrict__ Wqt,
                                                const unsigned short* __restrict__ Wkt,
                                                const unsigned short* __restrict__ Wvt,
                                                unsigned short* __restrict__ Qb,
                                                unsigned short* __restrict__ Kb,
                                                unsigned short* __restrict__ VbT) {
  __shared__ unsigned short Alds[128][72];
  __shared__ unsigned short Blds[128][72];
  const int z = blockIdx.z;
  const float* Ap = z == 0 ? Aq : z == 1 ? Ak : Av;
  const unsigned short* Wt = z == 0 ? Wqt : z == 1 ? Wkt : Wvt;
  unsigned short* Cb = z == 0 ? Qb : z == 1 ? Kb : VbT;
  const bool wt = (z == 2);
  const int tid = threadIdx.x;
  const int lane = tid & 63, wv = tid >> 6;
  const int wr = wv >> 1, wc = wv & 1;  // 2x2 waves, each 64x64
  const int l15 = lane & 15, lg = lane >> 4;
  const int row0 = blockIdx.x * 128, col0 = blockIdx.y * 128;
  f32x4 acc[4][4] = {};
  for (int k0 = 0; k0 < Dq; k0 += 64) {
    __syncthreads();
#pragma unroll
    for (int j = 0; j < 4; ++j) {
      int s = tid + j * 256;          // 1024 16B-segments per tile
      int r = s >> 3, c8 = (s & 7) * 8;
      const float* ap = Ap + (size_t)(row0 + r) * Dq + k0 + c8;
      float4 f0 = *(const float4*)ap;
      float4 f1 = *(const float4*)(ap + 4);
      short8 u;
      u[0] = (short)f2bf(f0.x); u[1] = (short)f2bf(f0.y);
      u[2] = (short)f2bf(f0.z); u[3] = (short)f2bf(f0.w);
      u[4] = (short)f2bf(f1.x); u[5] = (short)f2bf(f1.y);
      u[6] = (short)f2bf(f1.z); u[7] = (short)f2bf(f1.w);
      *(short8*)&Alds[r][c8] = u;
      *(uint4*)&Blds[r][c8] = *(const uint4*)&Wt[(size_t)(col0 + r) * Dq + k0 + c8];
    }
    __syncthreads();
#pragma unroll
    for (int kc = 0; kc < 2; ++kc) {
      short8 a[4], b[4];
#pragma unroll
      for (int mi = 0; mi < 4; ++mi)
        a[mi] = *(const short8*)&Alds[wr * 64 + mi * 16 + l15][kc * 32 + lg * 8];
#pragma unroll
      for (int ni = 0; ni < 4; ++ni)
        b[ni] = *(const short8*)&Blds[wc * 64 + ni * 16 + l15][kc * 32 + lg * 8];
#pragma unroll
      for (int mi = 0; mi < 4; ++mi)
#pragma unroll
        for (int ni = 0; ni < 4; ++ni)
          acc[mi][ni] = __builtin_amdgcn_mfma_f32_16x16x32_bf16(a[mi], b[ni], acc[mi][ni], 0, 0, 0);
    }
  }
  const int orow = row0 + wr * 64 + lg * 4;
  const int ocol = col0 + wc * 64 + l15;
  if (wt) {
    const int bidx = orow >> 11;
#pragma unroll
    for (int mi = 0; mi < 4; ++mi)
#pragma unroll
      for (int ni = 0; ni < 4; ++ni) {
        int gc = ocol + ni * 16;
        int s = (orow + mi * 16) & (Sq - 1);
        ushort4 w = {f2bf(acc[mi][ni][0]), f2bf(acc[mi][ni][1]),
                     f2bf(acc[mi][ni][2]), f2bf(acc[mi][ni][3])};
        *(ushort4*)&Cb[((size_t)(bidx * Dq + gc)) * Sq + s] = w;
      }
  } else {
#pragma unroll
    for (int mi = 0; mi < 4; ++mi)
#pragma unroll
      for (int ni = 0; ni < 4; ++ni)
#pragma unroll
        for (int rr = 0; rr < 4; ++rr) {
          int gr = orow + mi * 16 + rr, gc = ocol + ni * 16;
          Cb[(size_t)gr * Dq + gc] = f2bf(acc[mi][ni][rr]);
        }
  }
}

// ------- output projection + residual (fp32 out), 128x128 tile -------
__global__ __launch_bounds__(256) void gemm_wo(const unsigned short* __restrict__ Ab,
                                               const unsigned short* __restrict__ Wt,
                                               const float* __restrict__ res,
                                               float* __restrict__ Cf) {
  __shared__ unsigned short Alds[128][72];
  __shared__ unsigned short Blds[128][72];
  const int tid = threadIdx.x;
  const int lane = tid & 63, wv = tid >> 6;
  const int wr = wv >> 1, wc = wv & 1;
  const int l15 = lane & 15, lg = lane >> 4;
  const int row0 = blockIdx.x * 128, col0 = blockIdx.y * 128;
  f32x4 acc[4][4] = {};
  for (int k0 = 0; k0 < Dq; k0 += 64) {
    __syncthreads();
#pragma unroll
    for (int j = 0; j < 4; ++j) {
      int s = tid + j * 256;
      int r = s >> 3, c8 = (s & 7) * 8;
      *(uint4*)&Alds[r][c8] = *(const uint4*)&Ab[(size_t)(row0 + r) * Dq + k0 + c8];
      *(uint4*)&Blds[r][c8] = *(const uint4*)&Wt[(size_t)(col0 + r) * Dq + k0 + c8];
    }
    __syncthreads();
#pragma unroll
    for (int kc = 0; kc < 2; ++kc) {
      short8 a[4], b[4];
#pragma unroll
      for (int mi = 0; mi < 4; ++mi)
        a[mi] = *(const short8*)&Alds[wr * 64 + mi * 16 + l15][kc * 32 + lg * 8];
#pragma unroll
      for (int ni = 0; ni < 4; ++ni)
        b[ni] = *(const short8*)&Blds[wc * 64 + ni * 16 + l15][kc * 32 + lg * 8];
#pragma unroll
      for (int mi = 0; mi < 4; ++mi)
#pragma unroll
        for (int ni = 0; ni < 4; ++ni)
          acc[mi][ni] = __builtin_amdgcn_mfma_f32_16x16x32_bf16(a[mi], b[ni], acc[mi][ni], 0, 0, 0);
    }
  }
  const int orow = row0 + wr * 64 + lg * 4;
  const int ocol = col0 + wc * 64 + l15;
#pragma unroll
  for (int mi = 0; mi < 4; ++mi)
#pragma unroll
    for (int ni = 0; ni < 4; ++ni)
#pragma unroll
      for (int rr = 0; rr < 4; ++rr) {
        int gr = orow + mi * 16 + rr, gc = ocol + ni * 16;
        Cf[(size_t)gr * Dq + gc] = acc[mi][ni][rr] + res[(size_t)gr * Dq + gc];
      }
}

// ---------------- positional similarity (round-6 verified) ----------------
// simiB[b][q/16][k][q%16] fragment-blocked unnormalized exp + invsum[b][q].
__global__ __launch_bounds__(256) void possim(const unsigned short* __restrict__ qpe,
                                              const unsigned short* __restrict__ kpe,
                                              unsigned short* __restrict__ simiB,
                                              float* __restrict__ invsum) {
  __shared__ float wsum[4][16];
  const int tid = threadIdx.x, lane = tid & 63, wv = tid >> 6;
  const int l15 = lane & 15, lg = lane >> 4;
  const int b = blockIdx.y, q0 = blockIdx.x * 16;
  const unsigned short* qrow = qpe + ((size_t)(b * Sq + q0 + l15)) * Pq + lg * 8;
  short8 aq0 = *(const short8*)qrow;
  short8 aq1 = *(const short8*)(qrow + 32);
  unsigned short* sB = simiB + ((size_t)(b * (Sq / 16) + blockIdx.x)) * Sq * 16;
  float lsum[4] = {0.f, 0.f, 0.f, 0.f};
  for (int t = wv; t < Sq / 64; t += 4) {
    int k0 = t * 64;
    f32x4 sc[4] = {};
#pragma unroll
    for (int ng = 0; ng < 4; ++ng) {
      const unsigned short* krow = kpe + ((size_t)(b * Sq + k0 + ng * 16 + l15)) * Pq + lg * 8;
      short8 bk0 = *(const short8*)krow;
      short8 bk1 = *(const short8*)(krow + 32);
      sc[ng] = __builtin_amdgcn_mfma_f32_16x16x32_bf16(aq0, bk0, sc[ng], 0, 0, 0);
      sc[ng] = __builtin_amdgcn_mfma_f32_16x16x32_bf16(aq1, bk1, sc[ng], 0, 0, 0);
    }
#pragma unroll
    for (int ng = 0; ng < 4; ++ng) {
      float e0 = __expf(sc[ng][0]);
      float e1 = __expf(sc[ng][1]);
      float e2 = __expf(sc[ng][2]);
      float e3 = __expf(sc[ng][3]);
      lsum[0] += e0; lsum[1] += e1; lsum[2] += e2; lsum[3] += e3;
      ushort4 st = {f2bf(e0), f2bf(e1), f2bf(e2), f2bf(e3)};
      *(ushort4*)&sB[(size_t)(k0 + ng * 16 + l15) * 16 + lg * 4] = st;
    }
  }
  for (int rr = 0; rr < 4; ++rr)
    for (int m = 1; m < 16; m <<= 1) lsum[rr] += __shfl_xor(lsum[rr], m, 64);
  if (l15 == 0)
    for (int rr = 0; rr < 4; ++rr) wsum[wv][lg * 4 + rr] = lsum[rr];
  __syncthreads();
  if (tid < 16) {
    float tot = wsum[0][tid] + wsum[1][tid] + wsum[2][tid] + wsum[3][tid];
    invsum[b * Sq + q0 + tid] = 1.0f / tot;
  }
}

// ---------------- attention: round-20 base; hot-loop bf16 conversion via compiler cast ------
__global__ __launch_bounds__(512) void attn(const unsigned short* __restrict__ Qb,
                                            const unsigned short* __restrict__ Kb,
                                            const unsigned short* __restrict__ VbT,
                                            const unsigned short* __restrict__ simiB,
                                            const float* __restrict__ invsum,
                                            const float* __restrict__ mbias,
                                            unsigned short* __restrict__ O) {
  __shared__ unsigned short Klds[64][72];
  __shared__ unsigned short Vlds[64][72];
  __shared__ unsigned short Plds[8][16][72];
  const int tid = threadIdx.x, lane = tid & 63, wv = tid >> 6;  // wv 0..7
  const int l15 = lane & 15, lg = lane >> 4;
  const int id = blockIdx.x;
  const int h = id >> 6;          // 8 heads
  const int rem = id & 63;
  const int qt = rem >> 2;        // 16 q-tiles
  const int b = rem & 3;          // 4 batches
  const int q0 = qt * 128;
  const int qw = q0 + wv * 16;
  const int sr = tid >> 3, sc8 = (tid & 7) * 8;
  const unsigned short* Kg = Kb + ((size_t)(b * Sq + sr)) * Dq + h * HDq + sc8;   // +k0*Dq
  const unsigned short* Vg = VbT + ((size_t)(b * Dq + h * HDq + sr)) * Sq + sc8;  // +k0

  const unsigned short* qp = Qb + ((size_t)(b * Sq + qw + l15)) * Dq + h * HDq + lg * 8;
  short8 aq0 = *(const short8*)qp;
  short8 aq1 = *(const short8*)(qp + 32);
  float inv2[4];
#pragma unroll
  for (int rr = 0; rr < 4; ++rr)
    inv2[rr] = invsum[b * Sq + qw + lg * 4 + rr] * 1.442695041f;  // *log2e for exp2
  const unsigned short* sB =
      simiB + ((size_t)(b * (Sq / 16) + qt * 8 + wv)) * Sq * 16 + lg * 4;
  const float* Mb = mbias + b * Sq;

  // prologue: tile 0 into LDS
  {
    *(uint4*)&Klds[sr][sc8] = *(const uint4*)Kg;
    *(uint4*)&Vlds[sr][sc8] = *(const uint4*)Vg;
  }
  f32x4 oacc[4] = {};
  float lsum[4] = {0.f, 0.f, 0.f, 0.f};
  for (int t = 0; t < Sq / 64; ++t) {
    const int k0 = t * 64;
    __syncthreads();  // LDS tile t visible to all waves
    uint4 nk0, nv0;
    const bool more = (t < Sq / 64 - 1);
    if (more) {  // issue next-tile loads; held in regs across this tile's compute
      nk0 = *(const uint4*)(Kg + (size_t)(k0 + 64) * Dq);
      nv0 = *(const uint4*)(Vg + (k0 + 64));
    }
    ushort4 sv4[4];
    float mbf[4];
#pragma unroll
    for (int ng = 0; ng < 4; ++ng) {
      int kk = k0 + ng * 16 + l15;
      sv4[ng] = *(const ushort4*)&sB[(size_t)kk * 16];
      mbf[ng] = Mb[kk];
    }
    // QK^T (Q pre-scaled by 1/8 via Wq)
    f32x4 sc[4] = {};
    __builtin_amdgcn_s_setprio(1);
#pragma unroll
    for (int ng = 0; ng < 4; ++ng) {
      short8 bk0 = *(const short8*)&Klds[ng * 16 + l15][lg * 8];
      short8 bk1 = *(const short8*)&Klds[ng * 16 + l15][32 + lg * 8];
      sc[ng] = __builtin_amdgcn_mfma_f32_16x16x32_bf16(aq0, bk0, sc[ng], 0, 0, 0);
      sc[ng] = __builtin_amdgcn_mfma_f32_16x16x32_bf16(aq1, bk1, sc[ng], 0, 0, 0);
    }
    __builtin_amdgcn_s_setprio(0);
    // softmax numerator: p = exp2((sc*sv)*inv2 + mb); compiler-lowered bf16 conversion
#pragma unroll
    for (int ng = 0; ng < 4; ++ng) {
#pragma unroll
      for (int rr = 0; rr < 4; ++rr) {
        float sv = bf2f(rr == 0 ? sv4[ng].x : rr == 1 ? sv4[ng].y : rr == 2 ? sv4[ng].z
                                                                            : sv4[ng].w);
        float p = __builtin_amdgcn_exp2f(fmaf(sc[ng][rr] * sv, inv2[rr], mbf[ng]));
        lsum[rr] += p;
        Plds[wv][lg * 4 + rr][ng * 16 + l15] = f2bfh(p);
      }
    }
    short8 pa0 = *(const short8*)&Plds[wv][l15][lg * 8];
    short8 pa1 = *(const short8*)&Plds[wv][l15][32 + lg * 8];
    __builtin_amdgcn_s_setprio(1);
#pragma unroll
    for (int dg = 0; dg < 4; ++dg) {
      short8 bv0 = *(const short8*)&Vlds[dg * 16 + l15][lg * 8];
      short8 bv1 = *(const short8*)&Vlds[dg * 16 + l15][32 + lg * 8];
      oacc[dg] = __builtin_amdgcn_mfma_f32_16x16x32_bf16(pa0, bv0, oacc[dg], 0, 0, 0);
      oacc[dg] = __builtin_amdgcn_mfma_f32_16x16x32_bf16(pa1, bv1, oacc[dg], 0, 0, 0);
    }
    __builtin_amdgcn_s_setprio(0);
    __syncthreads();  // all waves done reading K/V tile t
    if (more) {
      *(uint4*)&Klds[sr][sc8] = nk0;
      *(uint4*)&Vlds[sr][sc8] = nv0;
    }
  }
#pragma unroll
  for (int rr = 0; rr < 4; ++rr)
    for (int m = 1; m < 16; m <<= 1) lsum[rr] += __shfl_xor(lsum[rr], m, 64);
#pragma unroll
  for (int dg = 0; dg < 4; ++dg)
    for (int rr = 0; rr < 4; ++rr) {
      int qg = qw + lg * 4 + rr;
      O[((size_t)(b * Sq + qg)) * Dq + h * HDq + dg * 16 + l15] = f2bfh(oacc[dg][rr] / lsum[rr]);
    }
}

// ---------------- LayerNorm in-place on d_out ----------------
__global__ __launch_bounds__(256) void lnorm(float* __restrict__ X,
                                             const float* __restrict__ gamma,
                                             const float* __restrict__ beta) {
  const int tid = threadIdx.x, lane = tid & 63, wv = tid >> 6;
  const int row = blockIdx.x * 4 + wv;
  float* xr = X + (size_t)row * Dq + lane * 8;
  float4 x0 = *(float4*)xr;
  float4 x1 = *(float4*)(xr + 4);
  float s = x0.x + x0.y + x0.z + x0.w + x1.x + x1.y + x1.z + x1.w;
  float s2 = x0.x * x0.x + x0.y * x0.y + x0.z * x0.z + x0.w * x0.w +
             x1.x * x1.x + x1.y * x1.y + x1.z * x1.z + x1.w * x1.w;
  for (int m = 1; m < 64; m <<= 1) {
    s += __shfl_xor(s, m, 64);
    s2 += __shfl_xor(s2, m, 64);
  }
  float mu = s * (1.0f / 512.0f);
  float var = s2 * (1.0f / 512.0f) - mu * mu;
  float rstd = rsqrtf(var + 1e-5f);
  const float* g = gamma + lane * 8;
  const float* be = beta + lane * 8;
  float4 y0, y1;
  y0.x = (x0.x - mu) * rstd * g[0] + be[0];
  y0.y = (x0.y - mu) * rstd * g[1] + be[1];
  y0.z = (x0.z - mu) * rstd * g[2] + be[2];
  y0.w = (x0.w - mu) * rstd * g[3] + be[3];
  y1.x = (x1.x - mu) * rstd * g[4] + be[4];
  y1.y = (x1.y - mu) * rstd * g[5] + be[5];
  y1.z = (x1.z - mu) * rstd * g[6] + be[6];
  y1.w = (x1.w - mu) * rstd * g[7] + be[7];
  *(float4*)xr = y0;
  *(float4*)(xr + 4) = y1;
}

extern "C" void kernel_launch(void* const* d_in, const int* in_sizes, int n_in,
                              void* d_out, int out_size, void* d_ws, size_t ws_size,
                              hipStream_t stream) {
  const float* query = (const float*)d_in[0];
  const float* key = (const float*)d_in[1];
  const float* value = (const float*)d_in[2];
  const float* qpe = (const float*)d_in[3];
  const float* kpe = (const float*)d_in[4];
  const int* mask = (const int*)d_in[5];
  const float* Wq = (const float*)d_in[6];
  const float* Wk = (const float*)d_in[7];
  const float* Wv = (const float*)d_in[8];
  const float* Wo = (const float*)d_in[9];
  const float* gamma = (const float*)d_in[10];
  const float* beta = (const float*)d_in[11];
  float* out = (float*)d_out;

  char* ws = (char*)d_ws;
  size_t off = 0;
  unsigned short* Qb = (unsigned short*)(ws + off); off += (size_t)Bq * Sq * Dq * 2;    // 8MB
  unsigned short* Kb = (unsigned short*)(ws + off); off += (size_t)Bq * Sq * Dq * 2;    // 8MB
  unsigned short* VbT = (unsigned short*)(ws + off); off += (size_t)Bq * Sq * Dq * 2;   // 8MB
  unsigned short* Wqt = (unsigned short*)(ws + off); off += (size_t)Dq * Dq * 2;
  unsigned short* Wkt = (unsigned short*)(ws + off); off += (size_t)Dq * Dq * 2;
  unsigned short* Wvt = (unsigned short*)(ws + off); off += (size_t)Dq * Dq * 2;
  unsigned short* Wot = (unsigned short*)(ws + off); off += (size_t)Dq * Dq * 2;
  unsigned short* simiB = (unsigned short*)(ws + off); off += (size_t)Bq * Sq * Sq * 2; // 32MB
  float* invsum = (float*)(ws + off); off += (size_t)Bq * Sq * 4;
  float* mbias = (float*)(ws + off); off += (size_t)Bq * Sq * 4;
  unsigned short* Ob = (unsigned short*)(ws + off); off += (size_t)Bq * Sq * Dq * 2;    // 8MB
  unsigned short* qpeb = (unsigned short*)(ws + off); off += (size_t)Bq * Sq * Pq * 2;  // 1MB
  unsigned short* kpeb = (unsigned short*)(ws + off); off += (size_t)Bq * Sq * Pq * 2;  // 1MB

  dim3 blk(256);
  prep_conv<<<dim3(544 + 1024), blk, 0, stream>>>(qpe, kpe, mask, Wq, Wk, Wv, Wo, qpeb, kpeb,
                                                  mbias, Wqt, Wkt, Wvt, Wot);
  possim<<<dim3(Sq / 16, Bq), blk, 0, stream>>>(qpeb, kpeb, simiB, invsum);
  gemm_qkv<<<dim3(64, 4, 3), blk, 0, stream>>>(query, key, value, Wqt, Wkt, Wvt, Qb, Kb, VbT);
  attn<<<dim3(512), dim3(512), 0, stream>>>(Qb, Kb, VbT, simiB, invsum, mbias, Ob);
  gemm_wo<<<dim3(64, 4), blk, 0, stream>>>(Ob, Wot, query, out);
  lnorm<<<dim3(Bq * Sq / 4), blk, 0, stream>>>(out, gamma, beta);
}

// Round 22
// 141.513 us; speedup vs baseline: 1.0890x; 1.0151x over previous
//
#include <hip/hip_runtime.h>
#include <hip/hip_bf16.h>

#define Bq 4
#define Sq 2048
#define Dq 512
#define Hq 8
#define HDq 64
#define Pq 64

typedef __attribute__((ext_vector_type(8))) short short8;
typedef __attribute__((ext_vector_type(4))) float f32x4;

// compiler-lowered bf16 conversion (RNE; backend emits native cvt + hazard handling)
__device__ inline unsigned short f2bfh(float f) {
  __hip_bfloat16 h = __float2bfloat16(f);
  return *reinterpret_cast<unsigned short*>(&h);
}
__device__ inline float bf2f(unsigned short s) {
  return __uint_as_float(((unsigned int)s) << 16);
}
__device__ inline short8 ld8f(const float* __restrict__ p) {
  const float4 a = *(const float4*)p;
  const float4 b = *(const float4*)(p + 4);
  short8 r;
  r[0] = (short)f2bfh(a.x); r[1] = (short)f2bfh(a.y); r[2] = (short)f2bfh(a.z); r[3] = (short)f2bfh(a.w);
  r[4] = (short)f2bfh(b.x); r[5] = (short)f2bfh(b.y); r[6] = (short)f2bfh(b.z); r[7] = (short)f2bfh(b.w);
  return r;
}

// ------- fused prep (qpe/kpe->bf16, mask->bias) + weight convert/transpose -------
__global__ __launch_bounds__(256) void prep_conv(const float* __restrict__ qpe,
                                                 const float* __restrict__ kpe,
                                                 const int* __restrict__ mask,
                                                 const float* __restrict__ Wq,
                                                 const float* __restrict__ Wk,
                                                 const float* __restrict__ Wv,
                                                 const float* __restrict__ Wo,
                                                 unsigned short* __restrict__ qpeb,
                                                 unsigned short* __restrict__ kpeb,
                                                 float* __restrict__ mb,
                                                 unsigned short* __restrict__ Wqt,
                                                 unsigned short* __restrict__ Wkt,
                                                 unsigned short* __restrict__ Wvt,
                                                 unsigned short* __restrict__ Wot) {
  __shared__ float tile[32][33];
  const int bid = blockIdx.x;
  if (bid < 256) {
    int i = bid * 256 + threadIdx.x;
    *(short8*)&qpeb[(size_t)i * 8] = ld8f(qpe + (size_t)i * 8);
  } else if (bid < 512) {
    int i = (bid - 256) * 256 + threadIdx.x;
    *(short8*)&kpeb[(size_t)i * 8] = ld8f(kpe + (size_t)i * 8);
  } else if (bid < 544) {
    int i = (bid - 512) * 256 + threadIdx.x;
    mb[i] = ((float)mask[i] - 1.0f) * 1.442695041e8f;  // (mask-1)*1e8*log2e
  } else {
    const int cid = bid - 544;
    const int x = cid & 15, y = (cid >> 4) & 15, z = cid >> 8;
    const float* W = z == 0 ? Wq : z == 1 ? Wk : z == 2 ? Wv : Wo;
    unsigned short* Wt = z == 0 ? Wqt : z == 1 ? Wkt : z == 2 ? Wvt : Wot;
    const float scale = (z == 0) ? 0.125f : 1.0f;  // fold 1/sqrt(HD) into Wq
    const int tx = threadIdx.x & 31, ty = threadIdx.x >> 5;
    const int n0 = x * 32, k0 = y * 32;
    for (int j = 0; j < 4; ++j)
      tile[ty + j * 8][tx] = W[(size_t)(k0 + ty + j * 8) * Dq + n0 + tx];
    __syncthreads();
    for (int j = 0; j < 4; ++j)
      Wt[(size_t)(n0 + ty + j * 8) * Dq + k0 + tx] = f2bfh(tile[tx][ty + j * 8] * scale);
  }
}

// ------- fused QKV projections: 128x128 tile, 4x4 acc/wave; z==2 writes V transposed -------
__global__ __launch_bounds__(256) void gemm_qkv(const float* __restrict__ Aq,
                                                const float* __restrict__ Ak,
                                                const float* __restrict__ Av,
                                                const unsigned short* __restrict__ Wqt,
                                                const unsigned short* __restrict__ Wkt,
                                                const unsigned short* __restrict__ Wvt,
                                                unsigned short* __restrict__ Qb,
                                                unsigned short* __restrict__ Kb,
                                                unsigned short* __restrict__ VbT) {
  __shared__ unsigned short Alds[128][72];
  __shared__ unsigned short Blds[128][72];
  const int z = blockIdx.z;
  const float* Ap = z == 0 ? Aq : z == 1 ? Ak : Av;
  const unsigned short* Wt = z == 0 ? Wqt : z == 1 ? Wkt : Wvt;
  unsigned short* Cb = z == 0 ? Qb : z == 1 ? Kb : VbT;
  const bool wt = (z == 2);
  const int tid = threadIdx.x;
  const int lane = tid & 63, wv = tid >> 6;
  const int wr = wv >> 1, wc = wv & 1;  // 2x2 waves, each 64x64
  const int l15 = lane & 15, lg = lane >> 4;
  const int row0 = blockIdx.x * 128, col0 = blockIdx.y * 128;
  f32x4 acc[4][4] = {};
  for (int k0 = 0; k0 < Dq; k0 += 64) {
    __syncthreads();
#pragma unroll
    for (int j = 0; j < 4; ++j) {
      int s = tid + j * 256;          // 1024 16B-segments per tile
      int r = s >> 3, c8 = (s & 7) * 8;
      const float* ap = Ap + (size_t)(row0 + r) * Dq + k0 + c8;
      float4 f0 = *(const float4*)ap;
      float4 f1 = *(const float4*)(ap + 4);
      short8 u;
      u[0] = (short)f2bfh(f0.x); u[1] = (short)f2bfh(f0.y);
      u[2] = (short)f2bfh(f0.z); u[3] = (short)f2bfh(f0.w);
      u[4] = (short)f2bfh(f1.x); u[5] = (short)f2bfh(f1.y);
      u[6] = (short)f2bfh(f1.z); u[7] = (short)f2bfh(f1.w);
      *(short8*)&Alds[r][c8] = u;
      *(uint4*)&Blds[r][c8] = *(const uint4*)&Wt[(size_t)(col0 + r) * Dq + k0 + c8];
    }
    __syncthreads();
#pragma unroll
    for (int kc = 0; kc < 2; ++kc) {
      short8 a[4], b[4];
#pragma unroll
      for (int mi = 0; mi < 4; ++mi)
        a[mi] = *(const short8*)&Alds[wr * 64 + mi * 16 + l15][kc * 32 + lg * 8];
#pragma unroll
      for (int ni = 0; ni < 4; ++ni)
        b[ni] = *(const short8*)&Blds[wc * 64 + ni * 16 + l15][kc * 32 + lg * 8];
#pragma unroll
      for (int mi = 0; mi < 4; ++mi)
#pragma unroll
        for (int ni = 0; ni < 4; ++ni)
          acc[mi][ni] = __builtin_amdgcn_mfma_f32_16x16x32_bf16(a[mi], b[ni], acc[mi][ni], 0, 0, 0);
    }
  }
  const int orow = row0 + wr * 64 + lg * 4;
  const int ocol = col0 + wc * 64 + l15;
  if (wt) {
    const int bidx = orow >> 11;
#pragma unroll
    for (int mi = 0; mi < 4; ++mi)
#pragma unroll
      for (int ni = 0; ni < 4; ++ni) {
        int gc = ocol + ni * 16;
        int s = (orow + mi * 16) & (Sq - 1);
        ushort4 w = {f2bfh(acc[mi][ni][0]), f2bfh(acc[mi][ni][1]),
                     f2bfh(acc[mi][ni][2]), f2bfh(acc[mi][ni][3])};
        *(ushort4*)&Cb[((size_t)(bidx * Dq + gc)) * Sq + s] = w;
      }
  } else {
#pragma unroll
    for (int mi = 0; mi < 4; ++mi)
#pragma unroll
      for (int ni = 0; ni < 4; ++ni)
#pragma unroll
        for (int rr = 0; rr < 4; ++rr) {
          int gr = orow + mi * 16 + rr, gc = ocol + ni * 16;
          Cb[(size_t)gr * Dq + gc] = f2bfh(acc[mi][ni][rr]);
        }
  }
}

// ------- output projection + residual (fp32 out), 128x128 tile -------
__global__ __launch_bounds__(256) void gemm_wo(const unsigned short* __restrict__ Ab,
                                               const unsigned short* __restrict__ Wt,
                                               const float* __restrict__ res,
                                               float* __restrict__ Cf) {
  __shared__ unsigned short Alds[128][72];
  __shared__ unsigned short Blds[128][72];
  const int tid = threadIdx.x;
  const int lane = tid & 63, wv = tid >> 6;
  const int wr = wv >> 1, wc = wv & 1;
  const int l15 = lane & 15, lg = lane >> 4;
  const int row0 = blockIdx.x * 128, col0 = blockIdx.y * 128;
  f32x4 acc[4][4] = {};
  for (int k0 = 0; k0 < Dq; k0 += 64) {
    __syncthreads();
#pragma unroll
    for (int j = 0; j < 4; ++j) {
      int s = tid + j * 256;
      int r = s >> 3, c8 = (s & 7) * 8;
      *(uint4*)&Alds[r][c8] = *(const uint4*)&Ab[(size_t)(row0 + r) * Dq + k0 + c8];
      *(uint4*)&Blds[r][c8] = *(const uint4*)&Wt[(size_t)(col0 + r) * Dq + k0 + c8];
    }
    __syncthreads();
#pragma unroll
    for (int kc = 0; kc < 2; ++kc) {
      short8 a[4], b[4];
#pragma unroll
      for (int mi = 0; mi < 4; ++mi)
        a[mi] = *(const short8*)&Alds[wr * 64 + mi * 16 + l15][kc * 32 + lg * 8];
#pragma unroll
      for (int ni = 0; ni < 4; ++ni)
        b[ni] = *(const short8*)&Blds[wc * 64 + ni * 16 + l15][kc * 32 + lg * 8];
#pragma unroll
      for (int mi = 0; mi < 4; ++mi)
#pragma unroll
        for (int ni = 0; ni < 4; ++ni)
          acc[mi][ni] = __builtin_amdgcn_mfma_f32_16x16x32_bf16(a[mi], b[ni], acc[mi][ni], 0, 0, 0);
    }
  }
  const int orow = row0 + wr * 64 + lg * 4;
  const int ocol = col0 + wc * 64 + l15;
#pragma unroll
  for (int mi = 0; mi < 4; ++mi)
#pragma unroll
    for (int ni = 0; ni < 4; ++ni)
#pragma unroll
      for (int rr = 0; rr < 4; ++rr) {
        int gr = orow + mi * 16 + rr, gc = ocol + ni * 16;
        Cf[(size_t)gr * Dq + gc] = acc[mi][ni][rr] + res[(size_t)gr * Dq + gc];
      }
}

// ---------------- positional similarity (round-6 verified layout) ----------------
// simiB[b][q/16][k][q%16] fragment-blocked unnormalized exp + invsum[b][q].
__global__ __launch_bounds__(256) void possim(const unsigned short* __restrict__ qpe,
                                              const unsigned short* __restrict__ kpe,
                                              unsigned short* __restrict__ simiB,
                                              float* __restrict__ invsum) {
  __shared__ float wsum[4][16];
  const int tid = threadIdx.x, lane = tid & 63, wv = tid >> 6;
  const int l15 = lane & 15, lg = lane >> 4;
  const int b = blockIdx.y, q0 = blockIdx.x * 16;
  const unsigned short* qrow = qpe + ((size_t)(b * Sq + q0 + l15)) * Pq + lg * 8;
  short8 aq0 = *(const short8*)qrow;
  short8 aq1 = *(const short8*)(qrow + 32);
  unsigned short* sB = simiB + ((size_t)(b * (Sq / 16) + blockIdx.x)) * Sq * 16;
  float lsum[4] = {0.f, 0.f, 0.f, 0.f};
  for (int t = wv; t < Sq / 64; t += 4) {
    int k0 = t * 64;
    f32x4 sc[4] = {};
#pragma unroll
    for (int ng = 0; ng < 4; ++ng) {
      const unsigned short* krow = kpe + ((size_t)(b * Sq + k0 + ng * 16 + l15)) * Pq + lg * 8;
      short8 bk0 = *(const short8*)krow;
      short8 bk1 = *(const short8*)(krow + 32);
      sc[ng] = __builtin_amdgcn_mfma_f32_16x16x32_bf16(aq0, bk0, sc[ng], 0, 0, 0);
      sc[ng] = __builtin_amdgcn_mfma_f32_16x16x32_bf16(aq1, bk1, sc[ng], 0, 0, 0);
    }
#pragma unroll
    for (int ng = 0; ng < 4; ++ng) {
      float e0 = __expf(sc[ng][0]);
      float e1 = __expf(sc[ng][1]);
      float e2 = __expf(sc[ng][2]);
      float e3 = __expf(sc[ng][3]);
      lsum[0] += e0; lsum[1] += e1; lsum[2] += e2; lsum[3] += e3;
      ushort4 st = {f2bfh(e0), f2bfh(e1), f2bfh(e2), f2bfh(e3)};
      *(ushort4*)&sB[(size_t)(k0 + ng * 16 + l15) * 16 + lg * 4] = st;
    }
  }
  for (int rr = 0; rr < 4; ++rr)
    for (int m = 1; m < 16; m <<= 1) lsum[rr] += __shfl_xor(lsum[rr], m, 64);
  if (l15 == 0)
    for (int rr = 0; rr < 4; ++rr) wsum[wv][lg * 4 + rr] = lsum[rr];
  __syncthreads();
  if (tid < 16) {
    float tot = wsum[0][tid] + wsum[1][tid] + wsum[2][tid] + wsum[3][tid];
    invsum[b * Sq + q0 + tid] = 1.0f / tot;
  }
}

// ---------------- attention: round-21 (best) unchanged ----------------
__global__ __launch_bounds__(512) void attn(const unsigned short* __restrict__ Qb,
                                            const unsigned short* __restrict__ Kb,
                                            const unsigned short* __restrict__ VbT,
                                            const unsigned short* __restrict__ simiB,
                                            const float* __restrict__ invsum,
                                            const float* __restrict__ mbias,
                                            unsigned short* __restrict__ O) {
  __shared__ unsigned short Klds[64][72];
  __shared__ unsigned short Vlds[64][72];
  __shared__ unsigned short Plds[8][16][72];
  const int tid = threadIdx.x, lane = tid & 63, wv = tid >> 6;  // wv 0..7
  const int l15 = lane & 15, lg = lane >> 4;
  const int id = blockIdx.x;
  const int h = id >> 6;          // 8 heads
  const int rem = id & 63;
  const int qt = rem >> 2;        // 16 q-tiles
  const int b = rem & 3;          // 4 batches
  const int q0 = qt * 128;
  const int qw = q0 + wv * 16;
  const int sr = tid >> 3, sc8 = (tid & 7) * 8;
  const unsigned short* Kg = Kb + ((size_t)(b * Sq + sr)) * Dq + h * HDq + sc8;   // +k0*Dq
  const unsigned short* Vg = VbT + ((size_t)(b * Dq + h * HDq + sr)) * Sq + sc8;  // +k0

  const unsigned short* qp = Qb + ((size_t)(b * Sq + qw + l15)) * Dq + h * HDq + lg * 8;
  short8 aq0 = *(const short8*)qp;
  short8 aq1 = *(const short8*)(qp + 32);
  float inv2[4];
#pragma unroll
  for (int rr = 0; rr < 4; ++rr)
    inv2[rr] = invsum[b * Sq + qw + lg * 4 + rr] * 1.442695041f;  // *log2e for exp2
  const unsigned short* sB =
      simiB + ((size_t)(b * (Sq / 16) + qt * 8 + wv)) * Sq * 16 + lg * 4;
  const float* Mb = mbias + b * Sq;

  // prologue: tile 0 into LDS
  {
    *(uint4*)&Klds[sr][sc8] = *(const uint4*)Kg;
    *(uint4*)&Vlds[sr][sc8] = *(const uint4*)Vg;
  }
  f32x4 oacc[4] = {};
  float lsum[4] = {0.f, 0.f, 0.f, 0.f};
  for (int t = 0; t < Sq / 64; ++t) {
    const int k0 = t * 64;
    __syncthreads();  // LDS tile t visible to all waves
    uint4 nk0, nv0;
    const bool more = (t < Sq / 64 - 1);
    if (more) {  // issue next-tile loads; held in regs across this tile's compute
      nk0 = *(const uint4*)(Kg + (size_t)(k0 + 64) * Dq);
      nv0 = *(const uint4*)(Vg + (k0 + 64));
    }
    ushort4 sv4[4];
    float mbf[4];
#pragma unroll
    for (int ng = 0; ng < 4; ++ng) {
      int kk = k0 + ng * 16 + l15;
      sv4[ng] = *(const ushort4*)&sB[(size_t)kk * 16];
      mbf[ng] = Mb[kk];
    }
    // QK^T (Q pre-scaled by 1/8 via Wq)
    f32x4 sc[4] = {};
    __builtin_amdgcn_s_setprio(1);
#pragma unroll
    for (int ng = 0; ng < 4; ++ng) {
      short8 bk0 = *(const short8*)&Klds[ng * 16 + l15][lg * 8];
      short8 bk1 = *(const short8*)&Klds[ng * 16 + l15][32 + lg * 8];
      sc[ng] = __builtin_amdgcn_mfma_f32_16x16x32_bf16(aq0, bk0, sc[ng], 0, 0, 0);
      sc[ng] = __builtin_amdgcn_mfma_f32_16x16x32_bf16(aq1, bk1, sc[ng], 0, 0, 0);
    }
    __builtin_amdgcn_s_setprio(0);
    // softmax numerator: p = exp2((sc*sv)*inv2 + mb); compiler-lowered bf16 conversion
#pragma unroll
    for (int ng = 0; ng < 4; ++ng) {
#pragma unroll
      for (int rr = 0; rr < 4; ++rr) {
        float sv = bf2f(rr == 0 ? sv4[ng].x : rr == 1 ? sv4[ng].y : rr == 2 ? sv4[ng].z
                                                                            : sv4[ng].w);
        float p = __builtin_amdgcn_exp2f(fmaf(sc[ng][rr] * sv, inv2[rr], mbf[ng]));
        lsum[rr] += p;
        Plds[wv][lg * 4 + rr][ng * 16 + l15] = f2bfh(p);
      }
    }
    short8 pa0 = *(const short8*)&Plds[wv][l15][lg * 8];
    short8 pa1 = *(const short8*)&Plds[wv][l15][32 + lg * 8];
    __builtin_amdgcn_s_setprio(1);
#pragma unroll
    for (int dg = 0; dg < 4; ++dg) {
      short8 bv0 = *(const short8*)&Vlds[dg * 16 + l15][lg * 8];
      short8 bv1 = *(const short8*)&Vlds[dg * 16 + l15][32 + lg * 8];
      oacc[dg] = __builtin_amdgcn_mfma_f32_16x16x32_bf16(pa0, bv0, oacc[dg], 0, 0, 0);
      oacc[dg] = __builtin_amdgcn_mfma_f32_16x16x32_bf16(pa1, bv1, oacc[dg], 0, 0, 0);
    }
    __builtin_amdgcn_s_setprio(0);
    __syncthreads();  // all waves done reading K/V tile t
    if (more) {
      *(uint4*)&Klds[sr][sc8] = nk0;
      *(uint4*)&Vlds[sr][sc8] = nv0;
    }
  }
#pragma unroll
  for (int rr = 0; rr < 4; ++rr)
    for (int m = 1; m < 16; m <<= 1) lsum[rr] += __shfl_xor(lsum[rr], m, 64);
#pragma unroll
  for (int dg = 0; dg < 4; ++dg)
    for (int rr = 0; rr < 4; ++rr) {
      int qg = qw + lg * 4 + rr;
      O[((size_t)(b * Sq + qg)) * Dq + h * HDq + dg * 16 + l15] = f2bfh(oacc[dg][rr] / lsum[rr]);
    }
}

// ---------------- LayerNorm in-place on d_out ----------------
__global__ __launch_bounds__(256) void lnorm(float* __restrict__ X,
                                             const float* __restrict__ gamma,
                                             const float* __restrict__ beta) {
  const int tid = threadIdx.x, lane = tid & 63, wv = tid >> 6;
  const int row = blockIdx.x * 4 + wv;
  float* xr = X + (size_t)row * Dq + lane * 8;
  float4 x0 = *(float4*)xr;
  float4 x1 = *(float4*)(xr + 4);
  float s = x0.x + x0.y + x0.z + x0.w + x1.x + x1.y + x1.z + x1.w;
  float s2 = x0.x * x0.x + x0.y * x0.y + x0.z * x0.z + x0.w * x0.w +
             x1.x * x1.x + x1.y * x1.y + x1.z * x1.z + x1.w * x1.w;
  for (int m = 1; m < 64; m <<= 1) {
    s += __shfl_xor(s, m, 64);
    s2 += __shfl_xor(s2, m, 64);
  }
  float mu = s * (1.0f / 512.0f);
  float var = s2 * (1.0f / 512.0f) - mu * mu;
  float rstd = rsqrtf(var + 1e-5f);
  const float* g = gamma + lane * 8;
  const float* be = beta + lane * 8;
  float4 y0, y1;
  y0.x = (x0.x - mu) * rstd * g[0] + be[0];
  y0.y = (x0.y - mu) * rstd * g[1] + be[1];
  y0.z = (x0.z - mu) * rstd * g[2] + be[2];
  y0.w = (x0.w - mu) * rstd * g[3] + be[3];
  y1.x = (x1.x - mu) * rstd * g[4] + be[4];
  y1.y = (x1.y - mu) * rstd * g[5] + be[5];
  y1.z = (x1.z - mu) * rstd * g[6] + be[6];
  y1.w = (x1.w - mu) * rstd * g[7] + be[7];
  *(float4*)xr = y0;
  *(float4*)(xr + 4) = y1;
}

extern "C" void kernel_launch(void* const* d_in, const int* in_sizes, int n_in,
                              void* d_out, int out_size, void* d_ws, size_t ws_size,
                              hipStream_t stream) {
  const float* query = (const float*)d_in[0];
  const float* key = (const float*)d_in[1];
  const float* value = (const float*)d_in[2];
  const float* qpe = (const float*)d_in[3];
  const float* kpe = (const float*)d_in[4];
  const int* mask = (const int*)d_in[5];
  const float* Wq = (const float*)d_in[6];
  const float* Wk = (const float*)d_in[7];
  const float* Wv = (const float*)d_in[8];
  const float* Wo = (const float*)d_in[9];
  const float* gamma = (const float*)d_in[10];
  const float* beta = (const float*)d_in[11];
  float* out = (float*)d_out;

  char* ws = (char*)d_ws;
  size_t off = 0;
  unsigned short* Qb = (unsigned short*)(ws + off); off += (size_t)Bq * Sq * Dq * 2;    // 8MB
  unsigned short* Kb = (unsigned short*)(ws + off); off += (size_t)Bq * Sq * Dq * 2;    // 8MB
  unsigned short* VbT = (unsigned short*)(ws + off); off += (size_t)Bq * Sq * Dq * 2;   // 8MB
  unsigned short* Wqt = (unsigned short*)(ws + off); off += (size_t)Dq * Dq * 2;
  unsigned short* Wkt = (unsigned short*)(ws + off); off += (size_t)Dq * Dq * 2;
  unsigned short* Wvt = (unsigned short*)(ws + off); off += (size_t)Dq * Dq * 2;
  unsigned short* Wot = (unsigned short*)(ws + off); off += (size_t)Dq * Dq * 2;
  unsigned short* simiB = (unsigned short*)(ws + off); off += (size_t)Bq * Sq * Sq * 2; // 32MB
  float* invsum = (float*)(ws + off); off += (size_t)Bq * Sq * 4;
  float* mbias = (float*)(ws + off); off += (size_t)Bq * Sq * 4;
  unsigned short* Ob = (unsigned short*)(ws + off); off += (size_t)Bq * Sq * Dq * 2;    // 8MB
  unsigned short* qpeb = (unsigned short*)(ws + off); off += (size_t)Bq * Sq * Pq * 2;  // 1MB
  unsigned short* kpeb = (unsigned short*)(ws + off); off += (size_t)Bq * Sq * Pq * 2;  // 1MB

  dim3 blk(256);
  prep_conv<<<dim3(544 + 1024), blk, 0, stream>>>(qpe, kpe, mask, Wq, Wk, Wv, Wo, qpeb, kpeb,
                                                  mbias, Wqt, Wkt, Wvt, Wot);
  possim<<<dim3(Sq / 16, Bq), blk, 0, stream>>>(qpeb, kpeb, simiB, invsum);
  gemm_qkv<<<dim3(64, 4, 3), blk, 0, stream>>>(query, key, value, Wqt, Wkt, Wvt, Qb, Kb, VbT);
  attn<<<dim3(512), dim3(512), 0, stream>>>(Qb, Kb, VbT, simiB, invsum, mbias, Ob);
  gemm_wo<<<dim3(64, 4), blk, 0, stream>>>(Ob, Wot, query, out);
  lnorm<<<dim3(Bq * Sq / 4), blk, 0, stream>>>(out, gamma, beta);
}